// Round 2
// baseline (8462.199 us; speedup 1.0000x reference)
//
#include <hip/hip_runtime.h>
#include <stdint.h>
#include <stddef.h>
#include <limits.h>

typedef _Float16 f16;
typedef _Float16 half8 __attribute__((ext_vector_type(8)));
typedef float floatx4 __attribute__((ext_vector_type(4)));
typedef unsigned long long u64;
typedef unsigned int u32;

#define MFMA(a,b,c) __builtin_amdgcn_mfma_f32_16x16x32_f16((a),(b),(c),0,0,0)

static constexpr int LMAX   = 1032;
static constexpr int TSTEPS = 1032;

// fixed-point packing for the rank all-reduce: Q20, bias 2^28 per contribution,
// exactly 4 contributions per element -> reader subtracts 2^30. Fields < 2^31,
// so no carry crosses the u64 field boundary.
static constexpr float FXSCALE = 1048576.0f;
static constexpr float FXINV   = 1.0f/1048576.0f;
static constexpr int   FXBIAS  = 1<<28;
static constexpr int   FXBIAS4 = 1<<30;

// ---------------- ws layout (bytes) ----------------
static constexpr size_t ZBYTES   = (size_t)256*32*LMAX*2;        // 16,908,288
static constexpr size_t OFF_ZA   = 0;                            // conv ping; later reused as y4x
static constexpr size_t OFF_ZB   = OFF_ZA + ZBYTES;
static constexpr size_t OFF_Y4   = OFF_ZA;                       // alias
static constexpr size_t OFF_WXF  = OFF_ZB + ZBYTES;              // Ui1@Vi1 frags, 128KB
static constexpr size_t OFF_VH1F = OFF_WXF  + 131072;            // 512KB each
static constexpr size_t OFF_VI2F = OFF_VH1F + 524288;
static constexpr size_t OFF_VH2F = OFF_VI2F + 524288;
static constexpr size_t OFF_UH1F = OFF_VH2F + 524288;            // 128KB each
static constexpr size_t OFF_UI2F = OFF_UH1F + 131072;
static constexpr size_t OFF_UH2F = OFF_UI2F + 131072;
static constexpr size_t OFF_B1   = OFF_UH2F + 131072;
static constexpr size_t OFF_B2   = OFF_B1 + 8192;
static constexpr size_t OFF_STATS= OFF_B2 + 8192;                // 1KB
static constexpr size_t OFF_AB   = OFF_STATS + 1024;             // 1KB
static constexpr size_t OFF_RINGS= OFF_AB + 1024;                // 3MB: 16 groups x 24576 u64
static constexpr size_t RING_BYTES = (size_t)16*24576*8;
static constexpr size_t OFF_H2F  = OFF_RINGS + RING_BYTES;       // 256KB h2 final
static constexpr size_t OFF_FLAGS= OFF_H2F + 262144;             // 2KB
// total ~39.4 MB

__device__ __forceinline__ float sigm(float x){ return 1.f/(1.f+__expf(-x)); }
// overflow-robust tanh: e^{-2|x|} form never produces inf/inf
__device__ __forceinline__ float tanh_f(float x){
  float ax = fabsf(x);
  float e = __expf(-2.f*ax);
  float r = (1.f - e)/(1.f + e);
  return (x < 0.f) ? -r : r;
}

__device__ __forceinline__ void sta64(void* p, u64 v){
  __hip_atomic_store((u64*)p, v, __ATOMIC_RELAXED, __HIP_MEMORY_SCOPE_AGENT);
}
__device__ __forceinline__ u64 lda64(const void* p){
  return __hip_atomic_load((const u64*)p, __ATOMIC_RELAXED, __HIP_MEMORY_SCOPE_AGENT);
}
__device__ __forceinline__ uint32_t ldf(const uint32_t* p){
  return __hip_atomic_load(p, __ATOMIC_RELAXED, __HIP_MEMORY_SCOPE_AGENT);
}
__device__ __forceinline__ void stf(uint32_t* p, uint32_t v){
  __hip_atomic_store(p, v, __ATOMIC_RELAXED, __HIP_MEMORY_SCOPE_AGENT);
}
__device__ __forceinline__ int4 ldg16i(const void* p){
  int4 r;
  asm volatile("global_load_dwordx4 %0, %1, off sc0 sc1" : "=v"(r) : "v"(p) : "memory");
  return r;
}
__device__ __forceinline__ void vmcnt0(){
  asm volatile("s_waitcnt vmcnt(0)" ::: "memory");
}
// rule #18: inline-asm waitcnt does NOT order register-only consumers (pack8 VALU);
// a sched_barrier(0) right after the waitcnt is the required fence.
__device__ __forceinline__ void schedbar(){
  __builtin_amdgcn_sched_barrier(0);
}

// poll one group's 8 flags with wave0: lanes 0..3 = producers >= tP, lanes 4..7 = consumers >= tC
__device__ __forceinline__ void pollWave8(const uint32_t* fl, int tP, int tC){
  const int lane = threadIdx.x & 63;
  int tgt = (lane < 4) ? tP : ((lane < 8) ? tC : INT_MIN);
  if (tgt <= 0) tgt = INT_MIN;
  while (true){
    uint32_t v = ldf(&fl[lane & 7]);
    if (__all((int)v >= tgt)) break;
    __builtin_amdgcn_s_sleep(1);
  }
}

// decode 8 packed u32 ring fields -> half8 A-fragment
__device__ __forceinline__ half8 pack8(int4 x, int4 y){
  half8 h;
  h[0] = (f16)((float)(x.x - FXBIAS4) * FXINV);
  h[1] = (f16)((float)(x.y - FXBIAS4) * FXINV);
  h[2] = (f16)((float)(x.z - FXBIAS4) * FXINV);
  h[3] = (f16)((float)(x.w - FXBIAS4) * FXINV);
  h[4] = (f16)((float)(y.x - FXBIAS4) * FXINV);
  h[5] = (f16)((float)(y.y - FXBIAS4) * FXINV);
  h[6] = (f16)((float)(y.z - FXBIAS4) * FXINV);
  h[7] = (f16)((float)(y.w - FXBIAS4) * FXINV);
  return h;
}
__device__ __forceinline__ u64 encodePair(float a, float b){
  int ia = (int)rintf(a * FXSCALE) + FXBIAS;
  int ib = (int)rintf(b * FXSCALE) + FXBIAS;
  return (u64)(u32)ia | ((u64)(u32)ib << 32);
}

// 4KB swizzled h-transpose tile: [16 rows][128 units] f16, 16B granules XOR-swizzled by row
__device__ __forceinline__ int hT_byte(int row, int u){
  return row*256 + ((((u>>3) ^ (row&7)))<<4) + (u&7)*2;
}
__device__ __forceinline__ half8 hT_frag(const uint8_t* hT, int lm, int q2, int lq){
  return *(const half8*)(hT + lm*256 + ((((q2<<2)+lq) ^ (lm&7))<<4));
}

// ---------------- zero: rings (3MB) + flags + stats ----------------
__global__ void k_zero(float* stats, uint32_t* flags, uint4* rings){
  int bx = blockIdx.x, tid = threadIdx.x;
  if (bx < 768){
    rings[(size_t)bx*256 + tid] = (uint4){0u,0u,0u,0u};
  } else {
    if (tid < 256){ stats[tid] = 0.f; flags[tid] = 0u; flags[tid+256] = 0u; }
  }
}

// ---------------- prep: Wx = Ui1(32x128)@Vi1(128x2048) -> frag layout ----------------
__global__ __launch_bounds__(256) void k_prep_wx(f16* __restrict__ dst, const float* __restrict__ U, const float* __restrict__ V){
  int id = blockIdx.x*256 + threadIdx.x;     // 8192
  int n = id >> 2, lq = id & 3;
  int nt = n >> 9, un = n & 511, b = un >> 7, w = (un >> 4) & 7, lm = un & 15;
  float s[8];
  #pragma unroll
  for (int j=0;j<8;++j) s[j]=0.f;
  for (int r=0;r<128;++r){
    float vv = V[(size_t)r*2048 + n];
    #pragma unroll
    for (int j=0;j<8;++j) s[j] += U[(size_t)(lq*8+j)*128 + r]*vv;
  }
  f16* o = dst + ((size_t)(((b*8+w)*4+nt)*64) + lq*16+lm)*8;
  #pragma unroll
  for (int j=0;j<8;++j) o[j] = (f16)s[j];
}

// ---------------- prep: V (128x2048) f32 -> B-frag layout [b][w][nt][q][lane][8] ----------------
__global__ __launch_bounds__(256) void k_prep_v(f16* __restrict__ dst, const float* __restrict__ V){
  int id = blockIdx.x*256 + threadIdx.x;     // 32768
  int n = id >> 4, kc = id & 15, q = kc >> 2, lq = kc & 3;
  int nt = n >> 9, un = n & 511, b = un >> 7, w = (un >> 4) & 7, lm = un & 15;
  f16* o = dst + ((size_t)((((b*8+w)*4+nt)*4+q)*64) + lq*16+lm)*8;
  #pragma unroll
  for (int j=0;j<8;++j) o[j] = (f16)V[(size_t)(q*32+lq*8+j)*2048 + n];
}

// ---------------- prep: U (512x128) f32 -> B-frag layout [b][w][q2][lane][8] ----------------
__global__ __launch_bounds__(256) void k_prep_u(f16* __restrict__ dst, const float* __restrict__ U){
  int id = blockIdx.x*256 + threadIdx.x;     // 8192
  int rn = id >> 6, rest = id & 63, b = rest >> 4, q2 = (rest >> 2) & 3, lq = rest & 3;
  int w = rn >> 4, lm = rn & 15;
  f16* o = dst + ((size_t)(((b*8+w)*4+q2)*64) + lq*16+lm)*8;
  #pragma unroll
  for (int j=0;j<8;++j) o[j] = (f16)U[(size_t)(b*128 + q2*32 + lq*8 + j)*128 + rn];
}

__global__ void k_prep_bias(float* dst, const float* a, const float* b){
  int idx = blockIdx.x*256 + threadIdx.x;
  if (idx < 2048) dst[idx] = a[idx] + b[idx];
}

// ---------------- conv block (verified R1-R3, unchanged) ----------------
__global__ __launch_bounds__(256) void k_conv(
    const float* __restrict__ x0, const f16* __restrict__ zin,
    const float* __restrict__ abp,
    const float* __restrict__ dwk, const float* __restrict__ dwb,
    const float* __restrict__ pwk, const float* __restrict__ pwb,
    f16* __restrict__ zout, float* __restrict__ stats,
    int Lin, int Cin)
{
  const int tid = threadIdx.x;
  const int b = blockIdx.y;
  const int l = blockIdx.x*256 + tid;
  const int Lout = Lin + 2;
  __shared__ float sPw[32*32], sDw[32*7], sDb[32], sPb[32], sAb[64];
  __shared__ float sRed[2][4][32];
  for (int i=tid; i<Cin*32; i+=256) sPw[i] = pwk[i];
  for (int i=tid; i<Cin*7;  i+=256) sDw[i] = dwk[i];
  if (tid < Cin) sDb[tid] = dwb[tid];
  if (tid >= 64 && tid < 96) sPb[tid-64] = pwb[tid-64];
  if (abp != nullptr && tid >= 128 && tid < 192) sAb[tid-128] = abp[tid-128];
  __syncthreads();

  float acc[32];
  #pragma unroll
  for (int o=0;o<32;++o) acc[o] = sPb[o];
  const bool act = (l < Lout);
  if (act){
    for (int c=0;c<Cin;++c){
      float s = sDb[c];
      #pragma unroll
      for (int k=0;k<7;++k){
        int li = l + k - 4;
        float v = 0.f;
        if (li >= 0 && li < Lin){
          if (x0) v = x0[((size_t)b*1024 + li)*16 + c];
          else {
            float z = (float)zin[((size_t)b*32 + c)*LMAX + li];
            v = fmaxf(sAb[c]*z + sAb[32+c], 0.f);
          }
        }
        s += sDw[c*7+k]*v;
      }
      #pragma unroll
      for (int o=0;o<32;++o) acc[o] += sPw[o*Cin + c]*s;
    }
    #pragma unroll
    for (int o=0;o<32;++o) zout[((size_t)b*32 + o)*LMAX + l] = (f16)acc[o];
  }
  const int lane = tid & 63, wv = tid >> 6;
  for (int o=0;o<32;++o){
    float v = act ? acc[o] : 0.f;
    float q = v*v;
    #pragma unroll
    for (int m=1;m<64;m<<=1){ v += __shfl_xor(v,m); q += __shfl_xor(q,m); }
    if (lane == 0){ sRed[0][wv][o] = v; sRed[1][wv][o] = q; }
  }
  __syncthreads();
  if (tid < 32){
    float v = sRed[0][0][tid]+sRed[0][1][tid]+sRed[0][2][tid]+sRed[0][3][tid];
    float q = sRed[1][0][tid]+sRed[1][1][tid]+sRed[1][2][tid]+sRed[1][3][tid];
    atomicAdd(&stats[tid], v);
    atomicAdd(&stats[32+tid], q);
  }
}

__global__ void k_bnfin(const float* __restrict__ stats, const float* __restrict__ g,
                        const float* __restrict__ beta, float* __restrict__ ab, float inv_n)
{
  int o = threadIdx.x;
  if (o < 32){
    float m = stats[o]*inv_n;
    float var = stats[32+o]*inv_n - m*m;
    float a = g[o]*rsqrtf(var + 1e-5f);
    ab[o] = a; ab[32+o] = beta[o] - m*a;
  }
}

// ---------------- y4 precompute (unchanged) ----------------
__global__ __launch_bounds__(256) void k_y4(const f16* __restrict__ z, const float* __restrict__ ab, f16* __restrict__ y){
  __shared__ f16 sT[32][264];
  __shared__ float sA[64];
  const int b = blockIdx.x, t0 = blockIdx.y*256, tid = threadIdx.x;
  if (tid < 64) sA[tid] = ab[tid];
  __syncthreads();
  #pragma unroll
  for (int i=0;i<8;++i){
    int f = tid + 256*i;
    int ch = f >> 6, tq = f & 63;
    int t = t0 + tq*4;
    if (t < 1032){
      u64 v = *(const u64*)(z + ((size_t)(b*32+ch)*1032 + t));
      union { u64 u; f16 h[4]; } cv; cv.u = v;
      float a = sA[ch], bb = sA[32+ch];
      #pragma unroll
      for (int j=0;j<4;++j) cv.h[j] = (f16)fmaxf(a*(float)cv.h[j] + bb, 0.f);
      *(u64*)&sT[ch][tq*4] = cv.u;
    }
  }
  __syncthreads();
  int t = t0 + tid;
  if (t < 1032){
    union { uint4 v; f16 h[8]; } o[4];
    #pragma unroll
    for (int k=0;k<4;++k)
      #pragma unroll
      for (int j=0;j<8;++j) o[k].h[j] = sT[k*8+j][t - t0];
    uint4* dst = (uint4*)(y + ((size_t)b*1032 + t)*32);
    #pragma unroll
    for (int k=0;k<4;++k) dst[k] = o[k].v;
  }
}

// ---------------- persistent low-rank 2-layer LSTM ----------------
// 16 groups (16 batch rows each) x (4 producer + 4 consumer blocks) of 512 threads.
// Exchange = rank-128 projections via packed fixed-point u64 atomics (all-reduce over 4 blocks).
__global__ __launch_bounds__(512,1) void k_lstm(
  const f16* __restrict__ y4x,
  const f16* __restrict__ WxF,  const f16* __restrict__ VhF1,
  const f16* __restrict__ ViF2, const f16* __restrict__ VhF2,
  const f16* __restrict__ UhF1, const f16* __restrict__ UiF2, const f16* __restrict__ UhF2,
  const float* __restrict__ bias1, const float* __restrict__ bias2,
  u64* __restrict__ rings, f16* __restrict__ h2fin,
  uint32_t* __restrict__ flags,
  const float* __restrict__ fcw, const float* __restrict__ fcb,
  float* __restrict__ outp)
{
  const int tid  = threadIdx.x;
  const int lane = tid & 63;
  const int w    = tid >> 6;          // wave 0..7: owns 16 units x all 4 gates
  const int lm   = lane & 15;
  const int lq   = lane >> 4;
  const int lq8  = lq*8;
  const int g    = blockIdx.x & 15;   // group
  const int idx  = blockIdx.x >> 4;   // 0..7
  const int role = idx >> 2;          // 0 = layer1 producer, 1 = layer2 consumer
  const int b    = idx & 3;           // unit-slice: units b*128..b*128+127

  __shared__ __align__(16) uint8_t hT[4096];   // [16 rows][128 units] f16, XOR-swizzled

  u64* GB = rings + (size_t)g*24576;           // R1: +0 (D=4), RI2: +4096 (D=16), R2: +20480 (D=4); slot=1024 u64
  uint32_t* fl = flags + (size_t)g*32;         // [0..3]=producers, [4..7]=consumers

  const int fb = (b*8 + w)*4;

  if (role == 0){
    // ---------------- layer-1 producer ----------------
    half8 wx[4], wv[4][4], uh[4], ui[4];
    float bs[4];
    #pragma unroll
    for (int nt=0; nt<4; ++nt){
      wx[nt] = *(const half8*)&WxF[(((size_t)(fb+nt))*64 + lane)*8];
      #pragma unroll
      for (int q=0;q<4;++q)
        wv[nt][q] = *(const half8*)&VhF1[((((size_t)(fb+nt))*4 + q)*64 + lane)*8];
      bs[nt] = bias1[nt*512 + b*128 + w*16 + lm];
    }
    #pragma unroll
    for (int q2=0;q2<4;++q2){
      uh[q2] = *(const half8*)&UhF1[(((size_t)(fb+q2))*64 + lane)*8];
      ui[q2] = *(const half8*)&UiF2[(((size_t)(fb+q2))*64 + lane)*8];
    }
    float creg[4] = {0.f,0.f,0.f,0.f};

    #pragma unroll 1
    for (int t=0; t<TSTEPS; ++t){
      half8 ya = *(const half8*)(y4x + ((size_t)(g*16+lm)*1032 + (size_t)t)*32 + lq8);
      if (w == 0) pollWave8(fl, t, t-13);   // peers' r1(t-1) ready; consumers within 13
      __syncthreads();
      { // zero ring slots for reuse (flag-ordered: drained before our flag t+1)
        int lin = b*512 + tid;
        u64* zp = (lin < 1024) ? (GB + (size_t)((t+2)&3)*1024 + lin)
                               : (GB + 4096 + (size_t)((t+2)&15)*1024 + (lin-1024));
        sta64(zp, 0ull);
      }
      int4 rr[8];
      if (t >= 1){
        const char* rp = (const char*)(GB + (size_t)((t-1)&3)*1024) + lm*512;
        #pragma unroll
        for (int q=0;q<4;++q){
          rr[2*q]   = ldg16i(rp + q*128 + lq*32);
          rr[2*q+1] = ldg16i(rp + q*128 + lq*32 + 16);
        }
      }
      floatx4 acc[4];
      #pragma unroll
      for (int nt=0;nt<4;++nt){
        acc[nt] = (floatx4){bs[nt],bs[nt],bs[nt],bs[nt]};
        acc[nt] = MFMA(ya, wx[nt], acc[nt]);
      }
      if (t >= 1){
        vmcnt0();
        schedbar();
        #pragma unroll
        for (int q=0;q<4;++q){
          half8 aq = pack8(rr[2*q], rr[2*q+1]);
          #pragma unroll
          for (int nt=0;nt<4;++nt) acc[nt] = MFMA(aq, wv[nt][q], acc[nt]);
        }
      }
      // in-register LSTM cell (lane holds all 4 gates of its unit, 4 batch rows)
      f16 hv[4];
      #pragma unroll
      for (int r=0;r<4;++r){
        float iv = acc[0][r], fv = acc[1][r], gv = acc[2][r], ov = acc[3][r];
        float c = sigm(fv)*creg[r] + sigm(iv)*tanh_f(gv);
        creg[r] = c;
        hv[r] = (f16)(sigm(ov)*tanh_f(c));
      }
      const int u = w*16 + lm;
      #pragma unroll
      for (int r=0;r<4;++r)
        *(f16*)(hT + hT_byte(lq*4+r, u)) = hv[r];
      __syncthreads();
      // partial projections p_h = h1_b @ Uh1_b, p_i = h1_b @ Ui2_b (per wave: 1 rank-tile)
      floatx4 pH = {0.f,0.f,0.f,0.f}, pI = {0.f,0.f,0.f,0.f};
      #pragma unroll
      for (int q2=0;q2<4;++q2){
        half8 ah = hT_frag(hT, lm, q2, lq);
        pH = MFMA(ah, uh[q2], pH);
        pI = MFMA(ah, ui[q2], pI);
      }
      float pHn[4], pIn[4];
      #pragma unroll
      for (int r=0;r<4;++r){ pHn[r] = __shfl_xor(pH[r],1); pIn[r] = __shfl_xor(pI[r],1); }
      if (!(lane & 1)){
        u64* s1 = GB + (size_t)(t&3)*1024;            // R1(t)
        u64* s2 = GB + 4096 + (size_t)(t&15)*1024;    // RI2(t)
        const int ub = (w*16 + lm) >> 1;
        #pragma unroll
        for (int r=0;r<4;++r){
          atomicAdd(s1 + (lq*4+r)*64 + ub, encodePair(pH[r], pHn[r]));
          atomicAdd(s2 + (lq*4+r)*64 + ub, encodePair(pI[r], pIn[r]));
        }
      }
      vmcnt0();
      __syncthreads();
      if (tid == 0) stf(&fl[b], (uint32_t)(t+1));
    }
  } else {
    // ---------------- layer-2 consumer ----------------
    half8 wi[4][4], wv2[4][4], u2[4];
    float bs[4];
    #pragma unroll
    for (int nt=0; nt<4; ++nt){
      #pragma unroll
      for (int q=0;q<4;++q){
        wi[nt][q]  = *(const half8*)&ViF2[((((size_t)(fb+nt))*4 + q)*64 + lane)*8];
        wv2[nt][q] = *(const half8*)&VhF2[((((size_t)(fb+nt))*4 + q)*64 + lane)*8];
      }
      bs[nt] = bias2[nt*512 + b*128 + w*16 + lm];
    }
    #pragma unroll
    for (int q2=0;q2<4;++q2)
      u2[q2] = *(const half8*)&UhF2[(((size_t)(fb+q2))*64 + lane)*8];
    float creg[4] = {0.f,0.f,0.f,0.f};

    #pragma unroll 1
    for (int t=0; t<TSTEPS; ++t){
      if (w == 0) pollWave8(fl, t+1, t);   // producers done t; consumer peers done t-1
      __syncthreads();
      { int lin = b*512 + tid;
        if (lin < 1024) sta64(GB + 20480 + (size_t)((t+2)&3)*1024 + lin, 0ull); }
      int4 ri[8], rh[8];
      {
        const char* rp = (const char*)(GB + 4096 + (size_t)(t&15)*1024) + lm*512;
        #pragma unroll
        for (int q=0;q<4;++q){
          ri[2*q]   = ldg16i(rp + q*128 + lq*32);
          ri[2*q+1] = ldg16i(rp + q*128 + lq*32 + 16);
        }
      }
      if (t >= 1){
        const char* rp = (const char*)(GB + 20480 + (size_t)((t-1)&3)*1024) + lm*512;
        #pragma unroll
        for (int q=0;q<4;++q){
          rh[2*q]   = ldg16i(rp + q*128 + lq*32);
          rh[2*q+1] = ldg16i(rp + q*128 + lq*32 + 16);
        }
      }
      floatx4 acc[4];
      #pragma unroll
      for (int nt=0;nt<4;++nt) acc[nt] = (floatx4){bs[nt],bs[nt],bs[nt],bs[nt]};
      if (t >= 1){ asm volatile("s_waitcnt vmcnt(8)" ::: "memory"); } else { vmcnt0(); }
      schedbar();
      #pragma unroll
      for (int q=0;q<4;++q){
        half8 aq = pack8(ri[2*q], ri[2*q+1]);
        #pragma unroll
        for (int nt=0;nt<4;++nt) acc[nt] = MFMA(aq, wi[nt][q], acc[nt]);
      }
      if (t >= 1){
        vmcnt0();
        schedbar();
        #pragma unroll
        for (int q=0;q<4;++q){
          half8 aq = pack8(rh[2*q], rh[2*q+1]);
          #pragma unroll
          for (int nt=0;nt<4;++nt) acc[nt] = MFMA(aq, wv2[nt][q], acc[nt]);
        }
      }
      f16 hv[4];
      #pragma unroll
      for (int r=0;r<4;++r){
        float iv = acc[0][r], fv = acc[1][r], gv = acc[2][r], ov = acc[3][r];
        float c = sigm(fv)*creg[r] + sigm(iv)*tanh_f(gv);
        creg[r] = c;
        hv[r] = (f16)(sigm(ov)*tanh_f(c));
      }
      const int u = w*16 + lm;
      #pragma unroll
      for (int r=0;r<4;++r)
        *(f16*)(hT + hT_byte(lq*4+r, u)) = hv[r];
      __syncthreads();
      floatx4 p2 = {0.f,0.f,0.f,0.f};
      #pragma unroll
      for (int q2=0;q2<4;++q2){
        half8 ah = hT_frag(hT, lm, q2, lq);
        p2 = MFMA(ah, u2[q2], p2);
      }
      float p2n[4];
      #pragma unroll
      for (int r=0;r<4;++r) p2n[r] = __shfl_xor(p2[r],1);
      if (!(lane & 1)){
        u64* s3 = GB + 20480 + (size_t)(t&3)*1024;   // R2(t)
        const int ub = (w*16 + lm) >> 1;
        #pragma unroll
        for (int r=0;r<4;++r)
          atomicAdd(s3 + (lq*4+r)*64 + ub, encodePair(p2[r], p2n[r]));
      }
      if (t == TSTEPS-1){
        int row = tid >> 5, ug = (tid & 31)*4;
        u64 v = *(const u64*)(hT + (row*256 + ((((ug>>3) ^ (row&7)))<<4) + (ug&7)*2));
        sta64((u64*)(h2fin + ((size_t)(g*16+row)*512 + b*128 + ug)), v);
      }
      vmcnt0();
      __syncthreads();
      if (tid == 0) stf(&fl[4+b], (uint32_t)(t+1));
    }
    // ---------- epilogue: out = h2(T-1) @ fc_w^T + fc_b ----------
    if (b == 0){
      if (w == 0) pollWave8(fl, 0, TSTEPS);
      __syncthreads();
      for (int e = tid; e < 160; e += 512){
        int row = e/10, nc = e%10;
        float s = fcb[nc];
        const float* wvv = fcw + (size_t)nc*512;
        const u64* hp = (const u64*)(h2fin + (size_t)(g*16+row)*512);
        for (int k4=0;k4<128;++k4){
          union { u64 uu; f16 h[4]; } cv; cv.uu = lda64(hp + k4);
          #pragma unroll
          for (int i2=0;i2<4;++i2) s += (float)cv.h[i2]*wvv[k4*4+i2];
        }
        outp[(size_t)(g*16+row)*10 + nc] = s;
      }
    }
  }
}

// ---------------- host ----------------
extern "C" void kernel_launch(void* const* d_in, const int* in_sizes, int n_in,
                              void* d_out, int out_size, void* d_ws, size_t ws_size,
                              hipStream_t stream)
{
  (void)in_sizes; (void)n_in; (void)out_size; (void)ws_size;
  const float* x = (const float*)d_in[0];
  auto F = [&](int i){ return (const float*)d_in[i]; };
  const float *Ui1=F(25), *Vi1=F(26), *Uh1=F(27), *Vh1=F(28), *bi1=F(29), *bh1=F(30);
  const float *Ui2=F(31), *Vi2=F(32), *Uh2=F(33), *Vh2=F(34), *bi2=F(35), *bh2=F(36);
  const float *fcw=F(37), *fcb=F(38);

  uint8_t* ws = (uint8_t*)d_ws;
  f16* zA   = (f16*)(ws + OFF_ZA);
  f16* zB   = (f16*)(ws + OFF_ZB);
  f16* y4x  = (f16*)(ws + OFF_Y4);
  f16* WxF  = (f16*)(ws + OFF_WXF);
  f16* Vh1F = (f16*)(ws + OFF_VH1F);
  f16* Vi2F = (f16*)(ws + OFF_VI2F);
  f16* Vh2F = (f16*)(ws + OFF_VH2F);
  f16* Uh1F = (f16*)(ws + OFF_UH1F);
  f16* Ui2F = (f16*)(ws + OFF_UI2F);
  f16* Uh2F = (f16*)(ws + OFF_UH2F);
  float* bias1 = (float*)(ws + OFF_B1);
  float* bias2 = (float*)(ws + OFF_B2);
  float* stats = (float*)(ws + OFF_STATS);
  float* ab    = (float*)(ws + OFF_AB);
  u64* rings   = (u64*)(ws + OFF_RINGS);
  f16* h2fin   = (f16*)(ws + OFF_H2F);
  uint32_t* flags = (uint32_t*)(ws + OFF_FLAGS);
  float* outp = (float*)d_out;

  k_zero<<<769, 256, 0, stream>>>(stats, flags, (uint4*)rings);

  k_prep_wx<<<32, 256, 0, stream>>>(WxF, Ui1, Vi1);
  k_prep_v<<<128, 256, 0, stream>>>(Vh1F, Vh1);
  k_prep_v<<<128, 256, 0, stream>>>(Vi2F, Vi2);
  k_prep_v<<<128, 256, 0, stream>>>(Vh2F, Vh2);
  k_prep_u<<<32, 256, 0, stream>>>(Uh1F, Uh1);
  k_prep_u<<<32, 256, 0, stream>>>(Ui2F, Ui2);
  k_prep_u<<<32, 256, 0, stream>>>(Uh2F, Uh2);
  k_prep_bias<<<8, 256, 0, stream>>>(bias1, bi1, bh1);
  k_prep_bias<<<8, 256, 0, stream>>>(bias2, bi2, bh2);

  dim3 cgrid(5, 256);
  k_conv<<<cgrid, 256, 0, stream>>>(x, nullptr, nullptr, F(1), F(2), F(3), F(4),
                                    zA, stats + 0*64, 1024, 16);
  k_bnfin<<<1, 64, 0, stream>>>(stats + 0*64, F(5), F(6), ab + 0*64, 1.f/(256.f*1026.f));
  k_conv<<<cgrid, 256, 0, stream>>>(nullptr, zA, ab + 0*64, F(7), F(8), F(9), F(10),
                                    zB, stats + 1*64, 1026, 32);
  k_bnfin<<<1, 64, 0, stream>>>(stats + 1*64, F(11), F(12), ab + 1*64, 1.f/(256.f*1028.f));
  k_conv<<<cgrid, 256, 0, stream>>>(nullptr, zB, ab + 1*64, F(13), F(14), F(15), F(16),
                                    zA, stats + 2*64, 1028, 32);
  k_bnfin<<<1, 64, 0, stream>>>(stats + 2*64, F(17), F(18), ab + 2*64, 1.f/(256.f*1030.f));
  k_conv<<<cgrid, 256, 0, stream>>>(nullptr, zA, ab + 2*64, F(19), F(20), F(21), F(22),
                                    zB, stats + 3*64, 1030, 32);
  k_bnfin<<<1, 64, 0, stream>>>(stats + 3*64, F(23), F(24), ab + 3*64, 1.f/(256.f*1032.f));

  k_y4<<<dim3(256,5), 256, 0, stream>>>(zB, ab + 3*64, y4x);

  k_lstm<<<128, 512, 0, stream>>>(y4x,
                                  WxF, Vh1F, Vi2F, Vh2F,
                                  Uh1F, Ui2F, Uh2F,
                                  bias1, bias2,
                                  rings, h2fin, flags,
                                  fcw, fcb, outp);
}

// Round 3
// 7794.379 us; speedup vs baseline: 1.0857x; 1.0857x over previous
//
#include <hip/hip_runtime.h>
#include <stdint.h>
#include <stddef.h>
#include <limits.h>

typedef _Float16 f16;
typedef _Float16 half8 __attribute__((ext_vector_type(8)));
typedef float floatx4 __attribute__((ext_vector_type(4)));
typedef unsigned long long u64;
typedef unsigned int u32;

#define MFMA(a,b,c) __builtin_amdgcn_mfma_f32_16x16x32_f16((a),(b),(c),0,0,0)

static constexpr int LMAX   = 1032;
static constexpr int TSTEPS = 1032;

// ---------------- ws layout (bytes) ----------------
static constexpr size_t ZBYTES   = (size_t)256*32*LMAX*2;        // 16,908,288
static constexpr size_t OFF_ZA   = 0;                            // conv ping; later reused as y4x
static constexpr size_t OFF_ZB   = OFF_ZA + ZBYTES;
static constexpr size_t OFF_Y4   = OFF_ZA;                       // alias
static constexpr size_t OFF_WXF  = OFF_ZB + ZBYTES;              // Ui1@Vi1 frags, 128KB
static constexpr size_t OFF_VH1F = OFF_WXF  + 131072;            // 512KB
static constexpr size_t OFF_VI2F = OFF_VH1F + 524288;            // 512KB
static constexpr size_t OFF_VH2F = OFF_VI2F + 524288;            // 512KB
static constexpr size_t OFF_UH1F = OFF_VH2F + 524288;            // 128KB each
static constexpr size_t OFF_UI2F = OFF_UH1F + 131072;
static constexpr size_t OFF_UH2F = OFF_UI2F + 131072;
static constexpr size_t OFF_B1   = OFF_UH2F + 131072;
static constexpr size_t OFF_B2   = OFF_B1 + 8192;
static constexpr size_t OFF_STATS= OFF_B2 + 8192;                // 1KB
static constexpr size_t OFF_AB   = OFF_STATS + 1024;             // 1KB
static constexpr size_t OFF_RINGS= OFF_AB + 1024;                // 3MB: 16 groups x 24576 u64
static constexpr size_t RING_BYTES = (size_t)16*24576*8;         // h1 ring 8x2048 + h2 ring 4x2048 (u64)
static constexpr size_t OFF_H2F  = OFF_RINGS + RING_BYTES;       // 256KB h2 final
static constexpr size_t OFF_FLAGS= OFF_H2F + 262144;             // 2KB
// total ~39.4 MB

__device__ __forceinline__ float sigm(float x){ return 1.f/(1.f+__expf(-x)); }
// overflow-robust tanh
__device__ __forceinline__ float tanh_f(float x){
  float ax = fabsf(x);
  float e = __expf(-2.f*ax);
  float r = (1.f - e)/(1.f + e);
  return (x < 0.f) ? -r : r;
}

__device__ __forceinline__ void sta64(void* p, u64 v){
  __hip_atomic_store((u64*)p, v, __ATOMIC_RELAXED, __HIP_MEMORY_SCOPE_AGENT);
}
__device__ __forceinline__ u64 lda64(const void* p){
  return __hip_atomic_load((const u64*)p, __ATOMIC_RELAXED, __HIP_MEMORY_SCOPE_AGENT);
}
__device__ __forceinline__ uint32_t ldf(const uint32_t* p){
  return __hip_atomic_load(p, __ATOMIC_RELAXED, __HIP_MEMORY_SCOPE_AGENT);
}
__device__ __forceinline__ void stf(uint32_t* p, uint32_t v){
  __hip_atomic_store(p, v, __ATOMIC_RELAXED, __HIP_MEMORY_SCOPE_AGENT);
}
__device__ __forceinline__ int4 ldg16i(const void* p){
  int4 r;
  asm volatile("global_load_dwordx4 %0, %1, off sc0 sc1" : "=v"(r) : "v"(p) : "memory");
  return r;
}
__device__ __forceinline__ void vmcnt0(){
  asm volatile("s_waitcnt vmcnt(0)" ::: "memory");
}

// poll group's flags: lanes 0..3 = producers >= tA, lanes 4..11 = consumers >= tB
__device__ __forceinline__ void pollF(const uint32_t* fl, int tA, int tB){
  const int lane = threadIdx.x & 63;
  int tgt = (lane < 4) ? tA : ((lane < 12) ? tB : INT_MIN);
  if (tgt <= 0) tgt = INT_MIN;
  while (true){
    uint32_t v = ldf(&fl[lane & 15]);
    if (__all((int)v >= tgt)) break;
    __builtin_amdgcn_s_sleep(1);
  }
}

// ---------------- zero: flags + stats (rings need no zeroing: plain overwrite) ----------------
__global__ void k_zero(float* stats, uint32_t* flags){
  int tid = threadIdx.x;
  stats[tid] = 0.f;
  flags[tid] = 0u;
  flags[tid+256] = 0u;
}

// ---------------- prep: Wx = Ui1(32x128)@Vi1(128x2048) -> frags [f=b*32+w*4+g][lane][8] ----------------
__global__ __launch_bounds__(256) void k_prep_wx(f16* __restrict__ dst, const float* __restrict__ U, const float* __restrict__ V){
  int id = blockIdx.x*256 + threadIdx.x;     // 8192
  int lane = id & 63, f = id >> 6;           // f<128
  int g = f & 3, w = (f>>2) & 7, b = f >> 5;
  int n = g*512 + b*128 + w*16 + (lane & 15);
  int k0 = (lane >> 4) * 8;
  float s[8];
  #pragma unroll
  for (int j=0;j<8;++j) s[j]=0.f;
  for (int r=0;r<128;++r){
    float vv = V[(size_t)r*2048 + n];
    #pragma unroll
    for (int j=0;j<8;++j) s[j] += U[(size_t)(k0+j)*128 + r]*vv;
  }
  f16* o = dst + ((size_t)f*64 + lane)*8;
  #pragma unroll
  for (int j=0;j<8;++j) o[j] = (f16)s[j];
}

// ---------------- prep: Vh1 (128x2048) -> frags [f=b*32+w*4+g][kq][lane][8] ----------------
__global__ __launch_bounds__(256) void k_prep_vh1(f16* __restrict__ dst, const float* __restrict__ V){
  int id = blockIdx.x*256 + threadIdx.x;     // 32768
  int lane = id & 63, fk = id >> 6;          // fk<512
  int kq = fk & 3, f = fk >> 2;
  int g = f & 3, w = (f>>2)&7, b = f>>5;
  int n = g*512 + b*128 + w*16 + (lane&15);
  int k0 = kq*32 + (lane>>4)*8;
  f16* o = dst + ((size_t)fk*64 + lane)*8;
  #pragma unroll
  for (int j=0;j<8;++j) o[j] = (f16)V[(size_t)(k0+j)*2048 + n];
}

// ---------------- prep: U (512x128) -> frags [nt*16+kq][lane][8] ----------------
__global__ __launch_bounds__(256) void k_prep_u(f16* __restrict__ dst, const float* __restrict__ U){
  int id = blockIdx.x*256 + threadIdx.x;     // 8192
  int lane = id & 63, fk = id >> 6;          // fk<128
  int kq = fk & 15, nt = fk >> 4;
  int n = nt*16 + (lane&15);
  int k0 = kq*32 + (lane>>4)*8;
  f16* o = dst + ((size_t)fk*64 + lane)*8;
  #pragma unroll
  for (int j=0;j<8;++j) o[j] = (f16)U[(size_t)(k0+j)*128 + n];
}

// ---------------- prep: Vi2/Vh2 (128x2048) -> frags [f=c*16+w*2+tau][kq][lane][8] ----------------
__global__ __launch_bounds__(256) void k_prep_v2(f16* __restrict__ dst, const float* __restrict__ V){
  int id = blockIdx.x*256 + threadIdx.x;     // 32768
  int lane = id & 63, fk = id >> 6;          // fk<512
  int kq = fk & 3, f = fk >> 2;
  int tau = f & 1, w = (f>>1)&7, c = f>>4;
  int tile = tau*8 + w, g = tile>>2, ut = w & 3;
  int n = g*512 + c*64 + ut*16 + (lane&15);
  int k0 = kq*32 + (lane>>4)*8;
  f16* o = dst + ((size_t)fk*64 + lane)*8;
  #pragma unroll
  for (int j=0;j<8;++j) o[j] = (f16)V[(size_t)(k0+j)*2048 + n];
}

__global__ void k_prep_bias(float* dst, const float* a, const float* b){
  int idx = blockIdx.x*256 + threadIdx.x;
  if (idx < 2048) dst[idx] = a[idx] + b[idx];
}

// ---------------- conv block (verified, unchanged) ----------------
__global__ __launch_bounds__(256) void k_conv(
    const float* __restrict__ x0, const f16* __restrict__ zin,
    const float* __restrict__ abp,
    const float* __restrict__ dwk, const float* __restrict__ dwb,
    const float* __restrict__ pwk, const float* __restrict__ pwb,
    f16* __restrict__ zout, float* __restrict__ stats,
    int Lin, int Cin)
{
  const int tid = threadIdx.x;
  const int b = blockIdx.y;
  const int l = blockIdx.x*256 + tid;
  const int Lout = Lin + 2;
  __shared__ float sPw[32*32], sDw[32*7], sDb[32], sPb[32], sAb[64];
  __shared__ float sRed[2][4][32];
  for (int i=tid; i<Cin*32; i+=256) sPw[i] = pwk[i];
  for (int i=tid; i<Cin*7;  i+=256) sDw[i] = dwk[i];
  if (tid < Cin) sDb[tid] = dwb[tid];
  if (tid >= 64 && tid < 96) sPb[tid-64] = pwb[tid-64];
  if (abp != nullptr && tid >= 128 && tid < 192) sAb[tid-128] = abp[tid-128];
  __syncthreads();

  float acc[32];
  #pragma unroll
  for (int o=0;o<32;++o) acc[o] = sPb[o];
  const bool act = (l < Lout);
  if (act){
    for (int c=0;c<Cin;++c){
      float s = sDb[c];
      #pragma unroll
      for (int k=0;k<7;++k){
        int li = l + k - 4;
        float v = 0.f;
        if (li >= 0 && li < Lin){
          if (x0) v = x0[((size_t)b*1024 + li)*16 + c];
          else {
            float z = (float)zin[((size_t)b*32 + c)*LMAX + li];
            v = fmaxf(sAb[c]*z + sAb[32+c], 0.f);
          }
        }
        s += sDw[c*7+k]*v;
      }
      #pragma unroll
      for (int o=0;o<32;++o) acc[o] += sPw[o*Cin + c]*s;
    }
    #pragma unroll
    for (int o=0;o<32;++o) zout[((size_t)b*32 + o)*LMAX + l] = (f16)acc[o];
  }
  const int lane = tid & 63, wv = tid >> 6;
  for (int o=0;o<32;++o){
    float v = act ? acc[o] : 0.f;
    float q = v*v;
    #pragma unroll
    for (int m=1;m<64;m<<=1){ v += __shfl_xor(v,m); q += __shfl_xor(q,m); }
    if (lane == 0){ sRed[0][wv][o] = v; sRed[1][wv][o] = q; }
  }
  __syncthreads();
  if (tid < 32){
    float v = sRed[0][0][tid]+sRed[0][1][tid]+sRed[0][2][tid]+sRed[0][3][tid];
    float q = sRed[1][0][tid]+sRed[1][1][tid]+sRed[1][2][tid]+sRed[1][3][tid];
    atomicAdd(&stats[tid], v);
    atomicAdd(&stats[32+tid], q);
  }
}

__global__ void k_bnfin(const float* __restrict__ stats, const float* __restrict__ g,
                        const float* __restrict__ beta, float* __restrict__ ab, float inv_n)
{
  int o = threadIdx.x;
  if (o < 32){
    float m = stats[o]*inv_n;
    float var = stats[32+o]*inv_n - m*m;
    float a = g[o]*rsqrtf(var + 1e-5f);
    ab[o] = a; ab[32+o] = beta[o] - m*a;
  }
}

// ---------------- y4 precompute (unchanged) ----------------
__global__ __launch_bounds__(256) void k_y4(const f16* __restrict__ z, const float* __restrict__ ab, f16* __restrict__ y){
  __shared__ f16 sT[32][264];
  __shared__ float sA[64];
  const int b = blockIdx.x, t0 = blockIdx.y*256, tid = threadIdx.x;
  if (tid < 64) sA[tid] = ab[tid];
  __syncthreads();
  #pragma unroll
  for (int i=0;i<8;++i){
    int f = tid + 256*i;
    int ch = f >> 6, tq = f & 63;
    int t = t0 + tq*4;
    if (t < 1032){
      u64 v = *(const u64*)(z + ((size_t)(b*32+ch)*1032 + t));
      union { u64 u; f16 h[4]; } cv; cv.u = v;
      float a = sA[ch], bb = sA[32+ch];
      #pragma unroll
      for (int j=0;j<4;++j) cv.h[j] = (f16)fmaxf(a*(float)cv.h[j] + bb, 0.f);
      *(u64*)&sT[ch][tq*4] = cv.u;
    }
  }
  __syncthreads();
  int t = t0 + tid;
  if (t < 1032){
    union { uint4 v; f16 h[8]; } o[4];
    #pragma unroll
    for (int k=0;k<4;++k)
      #pragma unroll
      for (int j=0;j<8;++j) o[k].h[j] = sT[k*8+j][t - t0];
    uint4* dst = (uint4*)(y + ((size_t)b*1032 + t)*32);
    #pragma unroll
    for (int k=0;k<4;++k) dst[k] = o[k].v;
  }
}

// ---------------- persistent low-rank 2-layer LSTM ----------------
// 16 groups x (4 producers: 128 units each; 8 consumers: 64 units each), 512 threads.
// Each block holds U-matrices in full -> computes full rank projection redundantly.
// Only h-slices are exchanged: plain relaxed stores, no atomics, no zeroing.
__global__ __launch_bounds__(512,2) void k_lstm(
  const f16* __restrict__ y4x,
  const f16* __restrict__ WxF,  const f16* __restrict__ VhF1,
  const f16* __restrict__ ViF2, const f16* __restrict__ VhF2,
  const f16* __restrict__ UhF1, const f16* __restrict__ UiF2, const f16* __restrict__ UhF2,
  const float* __restrict__ bias1, const float* __restrict__ bias2,
  u64* __restrict__ rings, f16* __restrict__ h2fin,
  uint32_t* __restrict__ flags,
  const float* __restrict__ fcw, const float* __restrict__ fcb,
  float* __restrict__ outp)
{
  const int tid  = threadIdx.x;
  const int lane = tid & 63;
  const int w    = tid >> 6;
  const int lm   = lane & 15;
  const int lq   = lane >> 4;
  const int lq8  = lq*8;
  const int g    = blockIdx.x & 15;
  const int idx  = blockIdx.x >> 4;        // 0..11

  __shared__ __align__(16) uint8_t hF1[16384];   // [4 quarters][16 rows][128 units] f16, swizzled
  __shared__ __align__(16) uint8_t rT[8192];     // producer: r1 [16][128]; consumer: ri(+0), rh(+4096)
  __shared__ __align__(16) uint8_t hF2[16384];   // consumers: [8 slices][16 rows][64 units]
  __shared__ float sG[4*16*68];                  // consumers: gate exchange

  u64* ringH1 = rings + (size_t)g*24576;         // [8 slots][2048 u64]
  u64* ringH2 = ringH1 + 8*2048;                 // [4 slots][2048 u64] (8 slices x 256)
  uint32_t* fl = flags + g*32;                   // [0..3] producers, [4..11] consumers

  if (idx < 4){
    // ================= layer-1 producer (units b*128 .. +127) =================
    const int b = idx;
    // resident weights
    half8 uh[16], wvx[4], wv[4][4];
    float bs[4];
    #pragma unroll
    for (int kq=0;kq<16;++kq) uh[kq] = *(const half8*)&UhF1[((size_t)(w*16+kq)*64 + lane)*8];
    #pragma unroll
    for (int g4=0;g4<4;++g4){
      int f = b*32 + w*4 + g4;
      wvx[g4] = *(const half8*)&WxF[((size_t)f*64 + lane)*8];
      #pragma unroll
      for (int kq=0;kq<4;++kq)
        wv[g4][kq] = *(const half8*)&VhF1[((size_t)(f*4+kq)*64 + lane)*8];
      bs[g4] = bias1[g4*512 + b*128 + w*16 + lm];
    }
    float creg[4] = {0.f,0.f,0.f,0.f};

    #pragma unroll 1
    for (int t=0; t<TSTEPS; ++t){
      half8 ya = *(const half8*)(y4x + ((size_t)(g*16+lm)*1032 + (size_t)t)*32 + lq8);
      pollF(fl, t, t-7);                   // peers stored h1(t-1); consumers within 7
      int4 d0, d1; int db0=0, db1=0;
      if (t >= 1){
        const char* sp = (const char*)(ringH1 + (size_t)((t-1)&7)*2048);
        int pb0 = tid >> 8; pb0 += (pb0 >= b);
        db0 = pb0*4096 + (tid & 255)*16;
        d0 = ldg16i(sp + db0);
        if (tid < 256){
          int i1 = 512 + tid; int pb1 = i1 >> 8; pb1 += (pb1 >= b);
          db1 = pb1*4096 + (i1 & 255)*16;
          d1 = ldg16i(sp + db1);
        }
      }
      // x-part gates while stage in flight
      floatx4 acc[4];
      #pragma unroll
      for (int g4=0;g4<4;++g4){
        acc[g4] = (floatx4){bs[g4],bs[g4],bs[g4],bs[g4]};
        acc[g4] = MFMA(ya, wvx[g4], acc[g4]);
      }
      if (t >= 1){
        vmcnt0();
        *(int4*)(hF1 + db0) = d0;
        if (tid < 256) *(int4*)(hF1 + db1) = d1;
      }
      __syncthreads();
      // full rank projection r1 = h1(t-1) @ Uh1
      if (t >= 1){
        floatx4 rc = {0.f,0.f,0.f,0.f};
        #pragma unroll
        for (int kq=0;kq<16;++kq){
          half8 ha = *(const half8*)(hF1 + (kq>>2)*4096 + lm*256 + ((((kq&3)*4 + lq) ^ (lm&7))<<4));
          rc = MFMA(ha, uh[kq], rc);
        }
        #pragma unroll
        for (int r=0;r<4;++r){
          int row = lq*4 + r, cc = w*16 + lm;
          *(f16*)(rT + row*256 + (((cc>>3) ^ (row&7))<<4) + (cc&7)*2) = (f16)rc[r];
        }
      }
      __syncthreads();
      if (t >= 1){
        #pragma unroll
        for (int kq=0;kq<4;++kq){
          half8 ra = *(const half8*)(rT + lm*256 + (((kq*4 + lq) ^ (lm&7))<<4));
          #pragma unroll
          for (int g4=0;g4<4;++g4) acc[g4] = MFMA(ra, wv[g4][kq], acc[g4]);
        }
      }
      // in-register cell: unit w*16+lm, rows lq*4+r
      #pragma unroll
      for (int r=0;r<4;++r){
        float cc = sigm(acc[1][r])*creg[r] + sigm(acc[0][r])*tanh_f(acc[2][r]);
        creg[r] = cc;
        float hh = sigm(acc[3][r])*tanh_f(cc);
        int row = lq*4 + r;
        int ch = w*2 + (lm>>3);
        *(f16*)(hF1 + b*4096 + row*256 + ((ch ^ (row&7))<<4) + (lm&7)*2) = (f16)hh;
      }
      __syncthreads();
      { u64 v = *(const u64*)(hF1 + b*4096 + tid*8);
        sta64(ringH1 + (size_t)(t&7)*2048 + b*512 + tid, v); }
      vmcnt0();
      __syncthreads();
      if (tid == 0) stf(&fl[b], (uint32_t)(t+1));
    }
  } else {
    // ================= layer-2 consumer (units c*64 .. +63) =================
    const int c = idx - 4;
    half8 ui2[16], uh2[16];
    float bs[2];
    #pragma unroll
    for (int kq=0;kq<16;++kq){
      ui2[kq] = *(const half8*)&UiF2[((size_t)(w*16+kq)*64 + lane)*8];
      uh2[kq] = *(const half8*)&UhF2[((size_t)(w*16+kq)*64 + lane)*8];
    }
    const f16* vi2b = ViF2 + ((size_t)(c*16 + w*2)*4)*512 + lane*8;
    const f16* vh2b = VhF2 + ((size_t)(c*16 + w*2)*4)*512 + lane*8;
    #pragma unroll
    for (int ta=0;ta<2;++ta){
      int tile = ta*8 + w, gg = tile>>2, ut = w & 3;
      bs[ta] = bias2[gg*512 + c*64 + ut*16 + lm];
    }
    float creg[2] = {0.f,0.f};
    const int crow = tid >> 5, cu0 = (tid & 31)*2;

    #pragma unroll 1
    for (int t=0; t<TSTEPS; ++t){
      pollF(fl, t+1, t);                   // producers stored h1(t); consumer peers stored h2(t-1)
      const char* s1 = (const char*)(ringH1 + (size_t)(t&7)*2048);
      int4 d0 = ldg16i(s1 + tid*16);
      int4 d1 = ldg16i(s1 + (512+tid)*16);
      int4 e0, e1; int eb0=0, eb1=0;
      if (t >= 1){
        const char* s2 = (const char*)(ringH2 + (size_t)((t-1)&3)*2048);
        { int s7 = tid >> 7; int ss = s7 + (s7 >= c);
          eb0 = ss*2048 + (tid & 127)*16;
          e0 = ldg16i(s2 + eb0); }
        if (tid < 384){
          int k1 = 512 + tid; int s7 = k1 >> 7; int ss = s7 + (s7 >= c);
          eb1 = ss*2048 + (k1 & 127)*16;
          e1 = ldg16i(s2 + eb1);
        }
      }
      // stream V frags (cached, L1-hot after first steps)
      half8 wviS[2][4], wvhS[2][4];
      #pragma unroll
      for (int ta=0;ta<2;++ta)
        #pragma unroll
        for (int kq=0;kq<4;++kq){
          wviS[ta][kq] = *(const half8*)(vi2b + (size_t)(ta*4+kq)*512);
          wvhS[ta][kq] = *(const half8*)(vh2b + (size_t)(ta*4+kq)*512);
        }
      vmcnt0();
      *(int4*)(hF1 + tid*16) = d0;
      *(int4*)(hF1 + (512+tid)*16) = d1;
      if (t >= 1){
        *(int4*)(hF2 + eb0) = e0;
        if (tid < 384) *(int4*)(hF2 + eb1) = e1;
      }
      __syncthreads();
      // rank projections
      floatx4 ri = {0.f,0.f,0.f,0.f}, rh = {0.f,0.f,0.f,0.f};
      #pragma unroll
      for (int kq=0;kq<16;++kq){
        half8 ha = *(const half8*)(hF1 + (kq>>2)*4096 + lm*256 + ((((kq&3)*4 + lq) ^ (lm&7))<<4));
        ri = MFMA(ha, ui2[kq], ri);
      }
      if (t >= 1){
        #pragma unroll
        for (int kq=0;kq<16;++kq){
          half8 hb = *(const half8*)(hF2 + (kq>>1)*2048 + lm*128 + (((((kq&1)*4 + lq)) ^ (lm&7))<<4));
          rh = MFMA(hb, uh2[kq], rh);
        }
      }
      #pragma unroll
      for (int r=0;r<4;++r){
        int row = lq*4 + r, cc = w*16 + lm;
        int off = row*256 + (((cc>>3) ^ (row&7))<<4) + (cc&7)*2;
        *(f16*)(rT + off) = (f16)ri[r];
        *(f16*)(rT + 4096 + off) = (f16)rh[r];
      }
      __syncthreads();
      floatx4 acc[2];
      #pragma unroll
      for (int ta=0;ta<2;++ta) acc[ta] = (floatx4){bs[ta],bs[ta],bs[ta],bs[ta]};
      #pragma unroll
      for (int kq=0;kq<4;++kq){
        half8 ra = *(const half8*)(rT + lm*256 + (((kq*4 + lq) ^ (lm&7))<<4));
        #pragma unroll
        for (int ta=0;ta<2;++ta) acc[ta] = MFMA(ra, wviS[ta][kq], acc[ta]);
      }
      if (t >= 1){
        #pragma unroll
        for (int kq=0;kq<4;++kq){
          half8 rb = *(const half8*)(rT + 4096 + lm*256 + (((kq*4 + lq) ^ (lm&7))<<4));
          #pragma unroll
          for (int ta=0;ta<2;++ta) acc[ta] = MFMA(rb, wvhS[ta][kq], acc[ta]);
        }
      }
      // gates -> LDS (waves 0-3 hold i,g; 4-7 hold f,o)
      #pragma unroll
      for (int ta=0;ta<2;++ta){
        int tile = ta*8 + w, gg = tile>>2, ut = w & 3;
        #pragma unroll
        for (int r=0;r<4;++r)
          sG[(gg*16 + lq*4 + r)*68 + ut*16 + lm] = acc[ta][r];
      }
      __syncthreads();
      // cell: 2 per thread
      #pragma unroll
      for (int e=0;e<2;++e){
        int u = cu0 + e;
        float iv = sG[(0*16+crow)*68 + u];
        float fv = sG[(1*16+crow)*68 + u];
        float gv = sG[(2*16+crow)*68 + u];
        float ov = sG[(3*16+crow)*68 + u];
        float cc = sigm(fv)*creg[e] + sigm(iv)*tanh_f(gv);
        creg[e] = cc;
        float hh = sigm(ov)*tanh_f(cc);
        *(f16*)(hF2 + c*2048 + crow*128 + ((((u>>3) ^ (crow&7)))<<4) + (u&7)*2) = (f16)hh;
      }
      __syncthreads();
      if (tid < 256){
        u64 v = *(const u64*)(hF2 + c*2048 + tid*8);
        sta64(ringH2 + (size_t)(t&3)*2048 + c*256 + tid, v);
        if (t == TSTEPS-1){
          int rr = tid >> 4, q = tid & 15;
          int chp = (q>>1) ^ (rr & 7);
          int ug = chp*8 + (q&1)*4;
          sta64((u64*)(h2fin + ((size_t)(g*16+rr)*512 + c*64 + ug)), v);
        }
      }
      vmcnt0();
      __syncthreads();
      if (tid == 0) stf(&fl[4+c], (uint32_t)(t+1));
    }
    // ---------- epilogue: out = h2(T-1) @ fc_w^T + fc_b ----------
    if (c == 0){
      pollF(fl, 0, TSTEPS);
      __syncthreads();
      for (int e = tid; e < 160; e += 512){
        int row = e/10, nc = e%10;
        float s = fcb[nc];
        const float* wvv = fcw + (size_t)nc*512;
        const u64* hp = (const u64*)(h2fin + (size_t)(g*16+row)*512);
        for (int k4=0;k4<128;++k4){
          union { u64 uu; f16 h[4]; } cv; cv.uu = lda64(hp + k4);
          #pragma unroll
          for (int i2=0;i2<4;++i2) s += (float)cv.h[i2]*wvv[k4*4+i2];
        }
        outp[(size_t)(g*16+row)*10 + nc] = s;
      }
    }
  }
}

// ---------------- host ----------------
extern "C" void kernel_launch(void* const* d_in, const int* in_sizes, int n_in,
                              void* d_out, int out_size, void* d_ws, size_t ws_size,
                              hipStream_t stream)
{
  (void)in_sizes; (void)n_in; (void)out_size; (void)ws_size;
  const float* x = (const float*)d_in[0];
  auto F = [&](int i){ return (const float*)d_in[i]; };
  const float *Ui1=F(25), *Vi1=F(26), *Uh1=F(27), *Vh1=F(28), *bi1=F(29), *bh1=F(30);
  const float *Ui2=F(31), *Vi2=F(32), *Uh2=F(33), *Vh2=F(34), *bi2=F(35), *bh2=F(36);
  const float *fcw=F(37), *fcb=F(38);

  uint8_t* ws = (uint8_t*)d_ws;
  f16* zA   = (f16*)(ws + OFF_ZA);
  f16* zB   = (f16*)(ws + OFF_ZB);
  f16* y4x  = (f16*)(ws + OFF_Y4);
  f16* WxF  = (f16*)(ws + OFF_WXF);
  f16* Vh1F = (f16*)(ws + OFF_VH1F);
  f16* Vi2F = (f16*)(ws + OFF_VI2F);
  f16* Vh2F = (f16*)(ws + OFF_VH2F);
  f16* Uh1F = (f16*)(ws + OFF_UH1F);
  f16* Ui2F = (f16*)(ws + OFF_UI2F);
  f16* Uh2F = (f16*)(ws + OFF_UH2F);
  float* bias1 = (float*)(ws + OFF_B1);
  float* bias2 = (float*)(ws + OFF_B2);
  float* stats = (float*)(ws + OFF_STATS);
  float* ab    = (float*)(ws + OFF_AB);
  u64* rings   = (u64*)(ws + OFF_RINGS);
  f16* h2fin   = (f16*)(ws + OFF_H2F);
  uint32_t* flags = (uint32_t*)(ws + OFF_FLAGS);
  float* outp = (float*)d_out;

  k_zero<<<1, 256, 0, stream>>>(stats, flags);

  k_prep_wx<<<32, 256, 0, stream>>>(WxF, Ui1, Vi1);
  k_prep_vh1<<<128, 256, 0, stream>>>(Vh1F, Vh1);
  k_prep_u<<<32, 256, 0, stream>>>(Uh1F, Uh1);
  k_prep_u<<<32, 256, 0, stream>>>(Ui2F, Ui2);
  k_prep_u<<<32, 256, 0, stream>>>(Uh2F, Uh2);
  k_prep_v2<<<128, 256, 0, stream>>>(Vi2F, Vi2);
  k_prep_v2<<<128, 256, 0, stream>>>(Vh2F, Vh2);
  k_prep_bias<<<8, 256, 0, stream>>>(bias1, bi1, bh1);
  k_prep_bias<<<8, 256, 0, stream>>>(bias2, bi2, bh2);

  dim3 cgrid(5, 256);
  k_conv<<<cgrid, 256, 0, stream>>>(x, nullptr, nullptr, F(1), F(2), F(3), F(4),
                                    zA, stats + 0*64, 1024, 16);
  k_bnfin<<<1, 64, 0, stream>>>(stats + 0*64, F(5), F(6), ab + 0*64, 1.f/(256.f*1026.f));
  k_conv<<<cgrid, 256, 0, stream>>>(nullptr, zA, ab + 0*64, F(7), F(8), F(9), F(10),
                                    zB, stats + 1*64, 1026, 32);
  k_bnfin<<<1, 64, 0, stream>>>(stats + 1*64, F(11), F(12), ab + 1*64, 1.f/(256.f*1028.f));
  k_conv<<<cgrid, 256, 0, stream>>>(nullptr, zB, ab + 1*64, F(13), F(14), F(15), F(16),
                                    zA, stats + 2*64, 1028, 32);
  k_bnfin<<<1, 64, 0, stream>>>(stats + 2*64, F(17), F(18), ab + 2*64, 1.f/(256.f*1030.f));
  k_conv<<<cgrid, 256, 0, stream>>>(nullptr, zA, ab + 2*64, F(19), F(20), F(21), F(22),
                                    zB, stats + 3*64, 1030, 32);
  k_bnfin<<<1, 64, 0, stream>>>(stats + 3*64, F(23), F(24), ab + 3*64, 1.f/(256.f*1032.f));

  k_y4<<<dim3(256,5), 256, 0, stream>>>(zB, ab + 3*64, y4x);

  k_lstm<<<192, 512, 0, stream>>>(y4x,
                                  WxF, Vh1F, Vi2F, Vh2F,
                                  Uh1F, Ui2F, Uh2F,
                                  bias1, bias2,
                                  rings, h2fin, flags,
                                  fcw, fcb, outp);
}

// Round 6
// 6714.541 us; speedup vs baseline: 1.2603x; 1.1608x over previous
//
#include <hip/hip_runtime.h>
#include <stdint.h>
#include <stddef.h>
#include <limits.h>

typedef _Float16 f16;
typedef _Float16 half8 __attribute__((ext_vector_type(8)));
typedef float floatx4 __attribute__((ext_vector_type(4)));
typedef unsigned long long u64;

#define MFMA(a,b,c) __builtin_amdgcn_mfma_f32_16x16x32_f16((a),(b),(c),0,0,0)

static constexpr int LMAX   = 1032;
static constexpr int TSTEPS = 1032;

// ---------------- ws layout (bytes) ----------------
static constexpr size_t ZBYTES   = (size_t)256*32*LMAX*2;        // 16,908,288
static constexpr size_t OFF_ZA   = 0;                            // conv ping; later reused as y4x
static constexpr size_t OFF_ZB   = OFF_ZA + ZBYTES;
static constexpr size_t OFF_Y4   = OFF_ZA;                       // alias
static constexpr size_t OFF_WH1F = OFF_ZB + ZBYTES;              // [128nt][16q][64lane][8] f16 = 2MB
static constexpr size_t OFF_WI2F = OFF_WH1F + (size_t)128*16*64*8*2;
static constexpr size_t OFF_WH2F = OFF_WI2F + (size_t)128*16*64*8*2;
static constexpr size_t OFF_WX1F = OFF_WH2F + (size_t)128*16*64*8*2;  // 128KB
static constexpr size_t OFF_B1   = OFF_WX1F + (size_t)128*64*8*2;
static constexpr size_t OFF_B2   = OFF_B1 + (size_t)2048*4;
static constexpr size_t OFF_STATS= OFF_B2 + (size_t)2048*4;
static constexpr size_t OFF_AB   = OFF_STATS + (size_t)4*64*4;
static constexpr size_t OFF_H1X  = OFF_AB + (size_t)4*64*4;           // [8g][8slot][32][512] f16 = 2MB
static constexpr size_t OFF_H2X  = OFF_H1X + (size_t)8*8*32*512*2;    // [8g][4slot][32][512] f16 = 1MB
static constexpr size_t OFF_FLAGS= OFF_H2X + (size_t)8*4*32*512*2;    // 8g x 32 u32 (128B/group)
// total ~43.3 MB

__device__ __forceinline__ float sigm(float x){ return 1.f/(1.f+__expf(-x)); }
__device__ __forceinline__ float tanh_f(float x){ float e=__expf(2.f*x); return (e-1.f)/(e+1.f); }

__device__ __forceinline__ void sta64(void* p, u64 v){
  __hip_atomic_store((u64*)p, v, __ATOMIC_RELAXED, __HIP_MEMORY_SCOPE_AGENT);
}
__device__ __forceinline__ u64 lda64(const void* p){
  return __hip_atomic_load((const u64*)p, __ATOMIC_RELAXED, __HIP_MEMORY_SCOPE_AGENT);
}
__device__ __forceinline__ uint32_t ldf(const uint32_t* p){
  return __hip_atomic_load(p, __ATOMIC_RELAXED, __HIP_MEMORY_SCOPE_AGENT);
}
__device__ __forceinline__ void stf(uint32_t* p, uint32_t v){
  __hip_atomic_store(p, v, __ATOMIC_RELAXED, __HIP_MEMORY_SCOPE_AGENT);
}
// 16B coherent (L1/L2-stale-safe) load, manually waited via vmcnt0()
__device__ __forceinline__ float4 ldg16(const void* p){
  float4 r;
  asm volatile("global_load_dwordx4 %0, %1, off sc0 sc1" : "=v"(r) : "v"(p) : "memory");
  return r;
}
__device__ __forceinline__ void vmcnt0(){
  asm volatile("s_waitcnt vmcnt(0)" ::: "memory");
}

// poll one 128B flag region with full wave0: lanes<16 check [lane] >= t1, lanes 16..31 check [lane] >= t2
__device__ __forceinline__ void pollWave(const uint32_t* fl, int t1, int t2){
  const int lane = threadIdx.x & 63;
  int tgt = (lane < 16) ? t1 : ((lane < 32) ? t2 : INT_MIN);
  if (tgt <= 0) tgt = INT_MIN;
  while (true){
    uint32_t v = ldf(&fl[lane & 31]);
    if (__all((int)v >= tgt)) break;
    __builtin_amdgcn_s_sleep(1);
  }
}

// poll only HALF of the flag region: flags [base .. base+15] >= tgt0
__device__ __forceinline__ void pollHalf(const uint32_t* fl, int base, int tgt0){
  const int lane = threadIdx.x & 63;
  int tgt = (lane < 16) ? tgt0 : INT_MIN;
  if (tgt <= 0) tgt = INT_MIN;
  while (true){
    uint32_t v = ldf(&fl[base + (lane & 15)]);
    if (__all((int)v >= tgt)) break;
    __builtin_amdgcn_s_sleep(1);
  }
}

// stage 32x512 f16: issue 8x16B coherent loads / thread
__device__ __forceinline__ void stageIssue(float4* r, const f16* src, int tid){
  #pragma unroll
  for (int i=0;i<8;++i){
    int qq = tid + 256*i;
    r[i] = ldg16(src + (size_t)qq*8);
  }
}
// write staged regs into swizzled LDS: chunk' = chunk ^ (row&15); wave writes one contiguous permuted row
__device__ __forceinline__ void stageWrite(uint8_t* base, const float4* r, int tid){
  #pragma unroll
  for (int i=0;i<8;++i){
    int qq = tid + 256*i;
    int row = qq >> 6, ck = qq & 63;
    int cs = ck ^ (row & 15);
    *(float4*)(base + ((row<<6) + cs)*16) = r[i];
  }
}
// A-frag read: 16B at (row, k-chunk q*4+lq), swizzled
__device__ __forceinline__ half8 fragLDS(const uint8_t* base, int row, int q, int lq){
  return *(const half8*)(base + (((row<<6)) + (((q<<2)+lq) ^ (row & 15)))*16);
}

// ---------------- zero flags/stats ----------------
__global__ void k_zero(float* stats, uint32_t* flags){
  int bx = blockIdx.x, tid = threadIdx.x;
  if (bx == 4){ if (tid < 256) stats[tid] = 0.f; }
  else flags[bx*256 + tid] = 0u;
}

// ---------------- weight prep: W = U(512x128) @ V(128x2048) -> frag layout ----------------
__global__ __launch_bounds__(256) void k_prep_W(f16* __restrict__ dst, const float* __restrict__ U, const float* __restrict__ V){
  __shared__ float sU[64][65];
  __shared__ float sV[64][68];
  const int tid = threadIdx.x;
  const int n0 = blockIdx.x*64, k0 = blockIdx.y*64;
  const int tx = tid & 15, ty = tid >> 4;
  float acc[4][4];
  #pragma unroll
  for (int a=0;a<4;++a){ acc[a][0]=0.f; acc[a][1]=0.f; acc[a][2]=0.f; acc[a][3]=0.f; }
  for (int rc=0; rc<2; ++rc){
    __syncthreads();
    #pragma unroll
    for (int i=0;i<16;++i){
      int f = tid + 256*i;
      int row = f>>6, col = f&63;
      sU[row][col] = U[(size_t)(k0+row)*128 + rc*64 + col];
      sV[row][col] = V[(size_t)(rc*64+row)*2048 + n0 + col];
    }
    __syncthreads();
    for (int rr=0; rr<64; ++rr){
      float4 bv = *(const float4*)&sV[rr][tx*4];
      #pragma unroll
      for (int a=0;a<4;++a){
        float av = sU[ty*4+a][rr];
        acc[a][0] += av*bv.x; acc[a][1] += av*bv.y; acc[a][2] += av*bv.z; acc[a][3] += av*bv.w;
      }
    }
  }
  #pragma unroll
  for (int a=0;a<4;++a){
    int k = k0 + ty*4 + a;
    int q = k>>5, lq2 = (k>>3)&3, j = k&7;
    #pragma unroll
    for (int c=0;c<4;++c){
      int n = n0 + tx*4 + c;
      int nt = n>>4, lmn = n&15;
      dst[(((size_t)nt*16 + q)*64 + (lq2*16+lmn))*8 + j] = (f16)acc[a][c];
    }
  }
}

__global__ __launch_bounds__(256) void k_prep_Wx(f16* __restrict__ dst, const float* __restrict__ U, const float* __restrict__ V){
  __shared__ float sU[32][129];
  __shared__ float sV[128][68];
  const int tid = threadIdx.x, n0 = blockIdx.x*64;
  for (int f=tid; f<32*128; f+=256) sU[f>>7][f&127] = U[f];
  for (int f=tid; f<128*64; f+=256) sV[f>>6][f&63] = V[(size_t)(f>>6)*2048 + n0 + (f&63)];
  __syncthreads();
  int nn = tid & 63, kb = (tid>>6)*8;
  int n = n0 + nn;
  float acc[8];
  #pragma unroll
  for (int i=0;i<8;++i) acc[i]=0.f;
  for (int r=0;r<128;++r){
    float v = sV[r][nn];
    #pragma unroll
    for (int i=0;i<8;++i) acc[i] += sU[kb+i][r]*v;
  }
  int nt = n>>4, lmn = n&15;
  #pragma unroll
  for (int i=0;i<8;++i){
    int k = kb+i;
    dst[((size_t)nt*64 + (((k>>3)&3)*16 + lmn))*8 + (k&7)] = (f16)acc[i];
  }
}

__global__ void k_prep_bias(float* dst, const float* a, const float* b){
  int idx = blockIdx.x*256 + threadIdx.x;
  if (idx < 2048) dst[idx] = a[idx] + b[idx];
}

// ---------------- conv block (verified R1-R3) ----------------
__global__ __launch_bounds__(256) void k_conv(
    const float* __restrict__ x0, const f16* __restrict__ zin,
    const float* __restrict__ abp,
    const float* __restrict__ dwk, const float* __restrict__ dwb,
    const float* __restrict__ pwk, const float* __restrict__ pwb,
    f16* __restrict__ zout, float* __restrict__ stats,
    int Lin, int Cin)
{
  const int tid = threadIdx.x;
  const int b = blockIdx.y;
  const int l = blockIdx.x*256 + tid;
  const int Lout = Lin + 2;
  __shared__ float sPw[32*32], sDw[32*7], sDb[32], sPb[32], sAb[64];
  __shared__ float sRed[2][4][32];
  for (int i=tid; i<Cin*32; i+=256) sPw[i] = pwk[i];
  for (int i=tid; i<Cin*7;  i+=256) sDw[i] = dwk[i];
  if (tid < Cin) sDb[tid] = dwb[tid];
  if (tid >= 64 && tid < 96) sPb[tid-64] = pwb[tid-64];
  if (abp != nullptr && tid >= 128 && tid < 192) sAb[tid-128] = abp[tid-128];
  __syncthreads();

  float acc[32];
  #pragma unroll
  for (int o=0;o<32;++o) acc[o] = sPb[o];
  const bool act = (l < Lout);
  if (act){
    for (int c=0;c<Cin;++c){
      float s = sDb[c];
      #pragma unroll
      for (int k=0;k<7;++k){
        int li = l + k - 4;
        float v = 0.f;
        if (li >= 0 && li < Lin){
          if (x0) v = x0[((size_t)b*1024 + li)*16 + c];
          else {
            float z = (float)zin[((size_t)b*32 + c)*LMAX + li];
            v = fmaxf(sAb[c]*z + sAb[32+c], 0.f);
          }
        }
        s += sDw[c*7+k]*v;
      }
      #pragma unroll
      for (int o=0;o<32;++o) acc[o] += sPw[o*Cin + c]*s;
    }
    #pragma unroll
    for (int o=0;o<32;++o) zout[((size_t)b*32 + o)*LMAX + l] = (f16)acc[o];
  }
  const int lane = tid & 63, wv = tid >> 6;
  for (int o=0;o<32;++o){
    float v = act ? acc[o] : 0.f;
    float q = v*v;
    #pragma unroll
    for (int m=1;m<64;m<<=1){ v += __shfl_xor(v,m); q += __shfl_xor(q,m); }
    if (lane == 0){ sRed[0][wv][o] = v; sRed[1][wv][o] = q; }
  }
  __syncthreads();
  if (tid < 32){
    float v = sRed[0][0][tid]+sRed[0][1][tid]+sRed[0][2][tid]+sRed[0][3][tid];
    float q = sRed[1][0][tid]+sRed[1][1][tid]+sRed[1][2][tid]+sRed[1][3][tid];
    atomicAdd(&stats[tid], v);
    atomicAdd(&stats[32+tid], q);
  }
}

__global__ void k_bnfin(const float* __restrict__ stats, const float* __restrict__ g,
                        const float* __restrict__ beta, float* __restrict__ ab, float inv_n)
{
  int o = threadIdx.x;
  if (o < 32){
    float m = stats[o]*inv_n;
    float var = stats[32+o]*inv_n - m*m;
    float a = g[o]*rsqrtf(var + 1e-5f);
    ab[o] = a; ab[32+o] = beta[o] - m*a;
  }
}

// ---------------- y4 precompute ----------------
__global__ __launch_bounds__(256) void k_y4(const f16* __restrict__ z, const float* __restrict__ ab, f16* __restrict__ y){
  __shared__ f16 sT[32][264];
  __shared__ float sA[64];
  const int b = blockIdx.x, t0 = blockIdx.y*256, tid = threadIdx.x;
  if (tid < 64) sA[tid] = ab[tid];
  __syncthreads();
  #pragma unroll
  for (int i=0;i<8;++i){
    int f = tid + 256*i;
    int ch = f >> 6, tq = f & 63;
    int t = t0 + tq*4;
    if (t < 1032){
      u64 v = *(const u64*)(z + ((size_t)(b*32+ch)*1032 + t));
      union { u64 u; f16 h[4]; } cv; cv.u = v;
      float a = sA[ch], bb = sA[32+ch];
      #pragma unroll
      for (int j=0;j<4;++j) cv.h[j] = (f16)fmaxf(a*(float)cv.h[j] + bb, 0.f);
      *(u64*)&sT[ch][tq*4] = cv.u;
    }
  }
  __syncthreads();
  int t = t0 + tid;
  if (t < 1032){
    union { uint4 v; f16 h[8]; } o[4];
    #pragma unroll
    for (int k=0;k<4;++k)
      #pragma unroll
      for (int j=0;j<8;++j) o[k].h[j] = sT[k*8+j][t - t0];
    uint4* dst = (uint4*)(y + ((size_t)b*1032 + t)*32);
    #pragma unroll
    for (int k=0;k<4;++k) dst[k] = o[k].v;
  }
}

// ---------------- persistent 2-layer LSTM: 8 groups x (16 L1 + 16 L2 blocks) ----------------
__global__ __launch_bounds__(256,1) void k_lstm(
  const f16* __restrict__ y4x,
  const f16* __restrict__ Wx1F, const f16* __restrict__ Wh1F,
  const f16* __restrict__ Wi2F, const f16* __restrict__ Wh2F,
  const float* __restrict__ bias1, const float* __restrict__ bias2,
  f16* __restrict__ h1x, f16* __restrict__ h2x,
  uint32_t* __restrict__ flags,
  const float* __restrict__ fcw, const float* __restrict__ fcb,
  float* __restrict__ outp)
{
  const int tid  = threadIdx.x;
  const int lane = tid & 63;
  const int w    = tid >> 6;      // wave = gate index s
  const int lm   = lane & 15;
  const int lq   = lane >> 4;
  const int lq8  = lq*8;
  const int g    = blockIdx.x & 7;              // group (XCD hint)
  const int idx  = blockIdx.x >> 3;             // 0..31
  const int role = idx >> 4;                    // 0 = layer1, 1 = layer2
  const int b    = idx & 15;                    // unit-slice: units b*32..b*32+31

  // 82,432 B static LDS -> exactly 1 block/CU (2x82,432 > 163,840)
  __shared__ __align__(16) uint8_t bufA[32768];
  __shared__ __align__(16) uint8_t bufB[32768];
  __shared__ float sGate[4*32*33];              // padded stride 33

  uint32_t* fl = flags + (size_t)g*32;          // [0..15]=FH1(producers), [16..31]=FHC(consumers)

  const float* biasL = role ? bias2 : bias1;
  float bs[2];
  #pragma unroll
  for (int ct=0; ct<2; ++ct) bs[ct] = biasL[w*512 + b*32 + ct*16 + lm];

  const int nt0 = w*32 + b*2;
  f16* hdst_base = role ? h2x + (size_t)g*4*32*512 : h1x + (size_t)g*8*32*512;

  float creg[4] = {0.f,0.f,0.f,0.f};
  const int cr_row = tid >> 3, cr_u0 = (tid & 7)*4;

  if (role == 0){
    // ---------------- layer-1 producer (unchanged, verified) ----------------
    half8 wx[2];
    half8 wB[2][16];
    #pragma unroll
    for (int ct=0; ct<2; ++ct){
      wx[ct] = *(const half8*)&Wx1F[((size_t)(nt0+ct)*64 + lane)*8];
      #pragma unroll
      for (int q=0;q<16;++q)
        wB[ct][q] = *(const half8*)&Wh1F[(((size_t)(nt0+ct)*16 + q)*64 + lane)*8];
    }
    #pragma unroll 1
    for (int t=0; t<TSTEPS; ++t){
      // y4 prefetch (independent of flags)
      half8 ya0 = *(const half8*)(y4x + ((size_t)(g*32 + lm)*1032 + t)*32 + lq8);
      half8 ya1 = *(const half8*)(y4x + ((size_t)(g*32 + 16 + lm)*1032 + t)*32 + lq8);
      if (w == 0) pollWave(fl, t, t-7);   // peers' h1(t-1); consumers done t-8
      __syncthreads();
      float4 st[8];
      if (t >= 1) stageIssue(st, h1x + ((size_t)(g*8 + ((t-1)&7))*32*512), tid);
      floatx4 acc[2][2];
      #pragma unroll
      for (int ct=0; ct<2; ++ct){
        acc[ct][0] = (floatx4){bs[ct],bs[ct],bs[ct],bs[ct]};
        acc[ct][1] = acc[ct][0];
      }
      acc[0][0] = MFMA(ya0, wx[0], acc[0][0]);
      acc[0][1] = MFMA(ya1, wx[0], acc[0][1]);
      acc[1][0] = MFMA(ya0, wx[1], acc[1][0]);
      acc[1][1] = MFMA(ya1, wx[1], acc[1][1]);
      if (t >= 1){
        vmcnt0();
        stageWrite(bufA, st, tid);
      }
      __syncthreads();
      if (t >= 1){
        #pragma unroll
        for (int q=0;q<16;++q){
          half8 a0 = fragLDS(bufA, lm,    q, lq);
          half8 a1 = fragLDS(bufA, 16+lm, q, lq);
          acc[0][0] = MFMA(a0, wB[0][q], acc[0][0]);
          acc[0][1] = MFMA(a1, wB[0][q], acc[0][1]);
          acc[1][0] = MFMA(a0, wB[1][q], acc[1][0]);
          acc[1][1] = MFMA(a1, wB[1][q], acc[1][1]);
        }
      }
      __syncthreads();
      #pragma unroll
      for (int ct=0; ct<2; ++ct)
        #pragma unroll
        for (int rt=0; rt<2; ++rt)
          #pragma unroll
          for (int r=0;r<4;++r)
            sGate[w*1056 + (rt*16 + lq*4 + r)*33 + ct*16 + lm] = acc[ct][rt][r];
      __syncthreads();
      {
        union { u64 uu; f16 h[4]; } hv;
        #pragma unroll
        for (int j=0;j<4;++j){
          int u = cr_u0 + j;
          float iv = sGate[0*1056 + cr_row*33 + u];
          float fv = sGate[1*1056 + cr_row*33 + u];
          float gv = sGate[2*1056 + cr_row*33 + u];
          float ov = sGate[3*1056 + cr_row*33 + u];
          float c = sigm(fv)*creg[j] + sigm(iv)*tanh_f(gv);
          creg[j] = c;
          hv.h[j] = (f16)(sigm(ov)*tanh_f(c));
        }
        f16* dst = hdst_base + (size_t)(t&7)*32*512 + cr_row*512 + b*32 + cr_u0;
        sta64(dst, hv.uu);
      }
      vmcnt0();
      __syncthreads();
      if (tid == 0) stf(&fl[b], (uint32_t)(t+1));
    }
  } else {
    // ---------------- layer-2 consumer: SPLIT-POLL restructure ----------------
    // B-part (h2(t-1) @ Wh2) depends only on consumer peers' flag(t) — compute it
    // while producers are still working on step t; then wait producers for A-part.
    half8 wA[2][16];
    half8 wB[2][16];
    #pragma unroll
    for (int ct=0; ct<2; ++ct)
      #pragma unroll
      for (int q=0;q<16;++q){
        wA[ct][q] = *(const half8*)&Wi2F[(((size_t)(nt0+ct)*16 + q)*64 + lane)*8];
        wB[ct][q] = *(const half8*)&Wh2F[(((size_t)(nt0+ct)*16 + q)*64 + lane)*8];
      }
    #pragma unroll 1
    for (int t=0; t<TSTEPS; ++t){
      // ---- phase 1: B-part, gated only on consumer peers >= t ----
      if (w == 0) pollHalf(fl, 16, t);    // consumer peers stored h2(t-1)
      __syncthreads();
      floatx4 acc[2][2];
      #pragma unroll
      for (int ct=0; ct<2; ++ct){
        acc[ct][0] = (floatx4){bs[ct],bs[ct],bs[ct],bs[ct]};
        acc[ct][1] = acc[ct][0];
      }
      if (t >= 1){
        float4 s1[8];
        stageIssue(s1, h2x + ((size_t)(g*4 + ((t-1)&3))*32*512), tid);
        vmcnt0();
        stageWrite(bufB, s1, tid);
        __syncthreads();
        #pragma unroll
        for (int q=0;q<16;++q){
          half8 a0 = fragLDS(bufB, lm,    q, lq);
          half8 a1 = fragLDS(bufB, 16+lm, q, lq);
          acc[0][0] = MFMA(a0, wB[0][q], acc[0][0]);
          acc[0][1] = MFMA(a1, wB[0][q], acc[0][1]);
          acc[1][0] = MFMA(a0, wB[1][q], acc[1][0]);
          acc[1][1] = MFMA(a1, wB[1][q], acc[1][1]);
        }
      }
      // ---- phase 2: A-part, gated on producers >= t+1 ----
      if (w == 0) pollHalf(fl, 0, t+1);   // producers stored h1(t)
      __syncthreads();
      {
        float4 s0[8];
        stageIssue(s0, h1x + ((size_t)(g*8 + (t&7))*32*512), tid);
        vmcnt0();
        stageWrite(bufA, s0, tid);
        __syncthreads();
        #pragma unroll
        for (int q=0;q<16;++q){
          half8 a0 = fragLDS(bufA, lm,    q, lq);
          half8 a1 = fragLDS(bufA, 16+lm, q, lq);
          acc[0][0] = MFMA(a0, wA[0][q], acc[0][0]);
          acc[0][1] = MFMA(a1, wA[0][q], acc[0][1]);
          acc[1][0] = MFMA(a0, wA[1][q], acc[1][0]);
          acc[1][1] = MFMA(a1, wA[1][q], acc[1][1]);
        }
      }
      __syncthreads();
      #pragma unroll
      for (int ct=0; ct<2; ++ct)
        #pragma unroll
        for (int rt=0; rt<2; ++rt)
          #pragma unroll
          for (int r=0;r<4;++r)
            sGate[w*1056 + (rt*16 + lq*4 + r)*33 + ct*16 + lm] = acc[ct][rt][r];
      __syncthreads();
      {
        union { u64 uu; f16 h[4]; } hv;
        #pragma unroll
        for (int j=0;j<4;++j){
          int u = cr_u0 + j;
          float iv = sGate[0*1056 + cr_row*33 + u];
          float fv = sGate[1*1056 + cr_row*33 + u];
          float gv = sGate[2*1056 + cr_row*33 + u];
          float ov = sGate[3*1056 + cr_row*33 + u];
          float c = sigm(fv)*creg[j] + sigm(iv)*tanh_f(gv);
          creg[j] = c;
          hv.h[j] = (f16)(sigm(ov)*tanh_f(c));
        }
        f16* dst = hdst_base + (size_t)(t&3)*32*512 + cr_row*512 + b*32 + cr_u0;
        sta64(dst, hv.uu);
      }
      vmcnt0();
      __syncthreads();
      if (tid == 0) stf(&fl[16 + b], (uint32_t)(t+1));
    }
    // ---------- epilogue: out = h2(T-1) @ fc_w^T + fc_b ----------
    if (b == 0){
      if (w == 0) pollWave(fl, 0, TSTEPS);
      __syncthreads();
      const f16* hbase = h2x + ((size_t)(g*4 + ((TSTEPS-1)&3))*32*512);
      for (int e = tid; e < 320; e += 256){
        int row = e/10, nc = e%10;
        float s = fcb[nc];
        const float* wv = fcw + (size_t)nc*512;
        const u64* hp = (const u64*)(hbase + row*512);
        for (int k4=0;k4<128;++k4){
          union { u64 uu; f16 h[4]; } cv; cv.uu = lda64(hp + k4);
          #pragma unroll
          for (int i2=0;i2<4;++i2) s += (float)cv.h[i2]*wv[k4*4+i2];
        }
        outp[(size_t)(g*32+row)*10 + nc] = s;
      }
    }
  }
}

// ---------------- host ----------------
extern "C" void kernel_launch(void* const* d_in, const int* in_sizes, int n_in,
                              void* d_out, int out_size, void* d_ws, size_t ws_size,
                              hipStream_t stream)
{
  (void)in_sizes; (void)n_in; (void)out_size; (void)ws_size;
  const float* x = (const float*)d_in[0];
  auto F = [&](int i){ return (const float*)d_in[i]; };
  const float *Ui1=F(25), *Vi1=F(26), *Uh1=F(27), *Vh1=F(28), *bi1=F(29), *bh1=F(30);
  const float *Ui2=F(31), *Vi2=F(32), *Uh2=F(33), *Vh2=F(34), *bi2=F(35), *bh2=F(36);
  const float *fcw=F(37), *fcb=F(38);

  uint8_t* ws = (uint8_t*)d_ws;
  f16* zA   = (f16*)(ws + OFF_ZA);
  f16* zB   = (f16*)(ws + OFF_ZB);
  f16* y4x  = (f16*)(ws + OFF_Y4);
  f16* Wh1F = (f16*)(ws + OFF_WH1F);
  f16* Wi2F = (f16*)(ws + OFF_WI2F);
  f16* Wh2F = (f16*)(ws + OFF_WH2F);
  f16* Wx1F = (f16*)(ws + OFF_WX1F);
  float* bias1 = (float*)(ws + OFF_B1);
  float* bias2 = (float*)(ws + OFF_B2);
  float* stats = (float*)(ws + OFF_STATS);
  float* ab    = (float*)(ws + OFF_AB);
  f16* h1x  = (f16*)(ws + OFF_H1X);
  f16* h2x  = (f16*)(ws + OFF_H2X);
  uint32_t* flags = (uint32_t*)(ws + OFF_FLAGS);
  float* outp = (float*)d_out;

  k_zero<<<5, 256, 0, stream>>>(stats, flags);

  k_prep_W<<<dim3(32,8), 256, 0, stream>>>(Wh1F, Uh1, Vh1);
  k_prep_W<<<dim3(32,8), 256, 0, stream>>>(Wi2F, Ui2, Vi2);
  k_prep_W<<<dim3(32,8), 256, 0, stream>>>(Wh2F, Uh2, Vh2);
  k_prep_Wx<<<32, 256, 0, stream>>>(Wx1F, Ui1, Vi1);
  k_prep_bias<<<8, 256, 0, stream>>>(bias1, bi1, bh1);
  k_prep_bias<<<8, 256, 0, stream>>>(bias2, bi2, bh2);

  dim3 cgrid(5, 256);
  k_conv<<<cgrid, 256, 0, stream>>>(x, nullptr, nullptr, F(1), F(2), F(3), F(4),
                                    zA, stats + 0*64, 1024, 16);
  k_bnfin<<<1, 64, 0, stream>>>(stats + 0*64, F(5), F(6), ab + 0*64, 1.f/(256.f*1026.f));
  k_conv<<<cgrid, 256, 0, stream>>>(nullptr, zA, ab + 0*64, F(7), F(8), F(9), F(10),
                                    zB, stats + 1*64, 1026, 32);
  k_bnfin<<<1, 64, 0, stream>>>(stats + 1*64, F(11), F(12), ab + 1*64, 1.f/(256.f*1028.f));
  k_conv<<<cgrid, 256, 0, stream>>>(nullptr, zB, ab + 1*64, F(13), F(14), F(15), F(16),
                                    zA, stats + 2*64, 1028, 32);
  k_bnfin<<<1, 64, 0, stream>>>(stats + 2*64, F(17), F(18), ab + 2*64, 1.f/(256.f*1030.f));
  k_conv<<<cgrid, 256, 0, stream>>>(nullptr, zA, ab + 2*64, F(19), F(20), F(21), F(22),
                                    zB, stats + 3*64, 1030, 32);
  k_bnfin<<<1, 64, 0, stream>>>(stats + 3*64, F(23), F(24), ab + 3*64, 1.f/(256.f*1032.f));

  k_y4<<<dim3(256,5), 256, 0, stream>>>(zB, ab + 3*64, y4x);

  k_lstm<<<256, 256, 0, stream>>>(y4x,
                                  Wx1F, Wh1F, Wi2F, Wh2F,
                                  bias1, bias2,
                                  h1x, h2x, flags,
                                  fcw, fcb, outp);
}

// Round 7
// 6116.965 us; speedup vs baseline: 1.3834x; 1.0977x over previous
//
#include <hip/hip_runtime.h>
#include <stdint.h>
#include <stddef.h>
#include <limits.h>

typedef _Float16 f16;
typedef _Float16 half8 __attribute__((ext_vector_type(8)));
typedef float floatx4 __attribute__((ext_vector_type(4)));
typedef unsigned long long u64;

#define MFMA(a,b,c) __builtin_amdgcn_mfma_f32_16x16x32_f16((a),(b),(c),0,0,0)

static constexpr int LMAX   = 1032;
static constexpr int TSTEPS = 1032;

// ---------------- ws layout (bytes) ----------------
static constexpr size_t ZBYTES   = (size_t)256*32*LMAX*2;        // 16,908,288
static constexpr size_t OFF_ZA   = 0;                            // conv ping; later reused as y4x
static constexpr size_t OFF_ZB   = OFF_ZA + ZBYTES;
static constexpr size_t OFF_Y4   = OFF_ZA;                       // alias
static constexpr size_t OFF_WH1F = OFF_ZB + ZBYTES;              // [128nt][16q][64lane][8] f16 = 2MB
static constexpr size_t OFF_WI2F = OFF_WH1F + (size_t)128*16*64*8*2;
static constexpr size_t OFF_WH2F = OFF_WI2F + (size_t)128*16*64*8*2;
static constexpr size_t OFF_WX1F = OFF_WH2F + (size_t)128*16*64*8*2;  // 128KB
static constexpr size_t OFF_B1   = OFF_WX1F + (size_t)128*64*8*2;
static constexpr size_t OFF_B2   = OFF_B1 + (size_t)2048*4;
static constexpr size_t OFF_STATS= OFF_B2 + (size_t)2048*4;
static constexpr size_t OFF_AB   = OFF_STATS + (size_t)4*64*4;
static constexpr size_t OFF_H1X  = OFF_AB + (size_t)4*64*4;           // [8g][8slot][32][512] f16 = 2MB
static constexpr size_t OFF_H2X  = OFF_H1X + (size_t)8*8*32*512*2;    // [8g][4slot][32][512] f16 = 1MB
static constexpr size_t OFF_FLAGS= OFF_H2X + (size_t)8*4*32*512*2;    // 8g x 32 u32 (128B/group)
// total ~43.3 MB

__device__ __forceinline__ float sigm(float x){ return 1.f/(1.f+__expf(-x)); }
__device__ __forceinline__ float tanh_f(float x){ float e=__expf(2.f*x); return (e-1.f)/(e+1.f); }

__device__ __forceinline__ void sta64(void* p, u64 v){
  __hip_atomic_store((u64*)p, v, __ATOMIC_RELAXED, __HIP_MEMORY_SCOPE_AGENT);
}
__device__ __forceinline__ u64 lda64(const void* p){
  return __hip_atomic_load((const u64*)p, __ATOMIC_RELAXED, __HIP_MEMORY_SCOPE_AGENT);
}
__device__ __forceinline__ uint32_t ldf(const uint32_t* p){
  return __hip_atomic_load(p, __ATOMIC_RELAXED, __HIP_MEMORY_SCOPE_AGENT);
}
__device__ __forceinline__ void stf(uint32_t* p, uint32_t v){
  __hip_atomic_store(p, v, __ATOMIC_RELAXED, __HIP_MEMORY_SCOPE_AGENT);
}
// 16B coherent (L1/L2-stale-safe) load, manually waited via waitcnt asm
__device__ __forceinline__ float4 ldg16(const void* p){
  float4 r;
  asm volatile("global_load_dwordx4 %0, %1, off sc0 sc1" : "=v"(r) : "v"(p) : "memory");
  return r;
}
__device__ __forceinline__ void vmcnt0(){
  asm volatile("s_waitcnt vmcnt(0)" ::: "memory");
}
__device__ __forceinline__ void vmcnt8(){
  asm volatile("s_waitcnt vmcnt(8)" ::: "memory");
}
__device__ __forceinline__ void lgkm0(){
  asm volatile("s_waitcnt lgkmcnt(0)" ::: "memory");
}
__device__ __forceinline__ void schedbar(){
  __builtin_amdgcn_sched_barrier(0);
}

// poll one 128B flag region with full wave0: lanes<16 check [lane] >= t1, lanes 16..31 check [lane] >= t2
__device__ __forceinline__ void pollWave(const uint32_t* fl, int t1, int t2){
  const int lane = threadIdx.x & 63;
  int tgt = (lane < 16) ? t1 : ((lane < 32) ? t2 : INT_MIN);
  if (tgt <= 0) tgt = INT_MIN;
  while (true){
    uint32_t v = ldf(&fl[lane & 31]);
    if (__all((int)v >= tgt)) break;
    __builtin_amdgcn_s_sleep(1);
  }
}

// stage 32x512 f16: issue 8x16B coherent loads / thread
__device__ __forceinline__ void stageIssue(float4* r, const f16* src, int tid){
  #pragma unroll
  for (int i=0;i<8;++i){
    int qq = tid + 256*i;
    r[i] = ldg16(src + (size_t)qq*8);
  }
}
// write staged regs into swizzled LDS: chunk' = chunk ^ (row&15); wave writes one contiguous permuted row
__device__ __forceinline__ void stageWrite(uint8_t* base, const float4* r, int tid){
  #pragma unroll
  for (int i=0;i<8;++i){
    int qq = tid + 256*i;
    int row = qq >> 6, ck = qq & 63;
    int cs = ck ^ (row & 15);
    *(float4*)(base + ((row<<6) + cs)*16) = r[i];
  }
}
// A-frag read: 16B at (row, k-chunk q*4+lq), swizzled
__device__ __forceinline__ half8 fragLDS(const uint8_t* base, int row, int q, int lq){
  return *(const half8*)(base + (((row<<6)) + (((q<<2)+lq) ^ (row & 15)))*16);
}

// ---------------- zero flags/stats ----------------
__global__ void k_zero(float* stats, uint32_t* flags){
  int bx = blockIdx.x, tid = threadIdx.x;
  if (bx == 4){ if (tid < 256) stats[tid] = 0.f; }
  else flags[bx*256 + tid] = 0u;
}

// ---------------- weight prep: W = U(512x128) @ V(128x2048) -> frag layout ----------------
__global__ __launch_bounds__(256) void k_prep_W(f16* __restrict__ dst, const float* __restrict__ U, const float* __restrict__ V){
  __shared__ float sU[64][65];
  __shared__ float sV[64][68];
  const int tid = threadIdx.x;
  const int n0 = blockIdx.x*64, k0 = blockIdx.y*64;
  const int tx = tid & 15, ty = tid >> 4;
  float acc[4][4];
  #pragma unroll
  for (int a=0;a<4;++a){ acc[a][0]=0.f; acc[a][1]=0.f; acc[a][2]=0.f; acc[a][3]=0.f; }
  for (int rc=0; rc<2; ++rc){
    __syncthreads();
    #pragma unroll
    for (int i=0;i<16;++i){
      int f = tid + 256*i;
      int row = f>>6, col = f&63;
      sU[row][col] = U[(size_t)(k0+row)*128 + rc*64 + col];
      sV[row][col] = V[(size_t)(rc*64+row)*2048 + n0 + col];
    }
    __syncthreads();
    for (int rr=0; rr<64; ++rr){
      float4 bv = *(const float4*)&sV[rr][tx*4];
      #pragma unroll
      for (int a=0;a<4;++a){
        float av = sU[ty*4+a][rr];
        acc[a][0] += av*bv.x; acc[a][1] += av*bv.y; acc[a][2] += av*bv.z; acc[a][3] += av*bv.w;
      }
    }
  }
  #pragma unroll
  for (int a=0;a<4;++a){
    int k = k0 + ty*4 + a;
    int q = k>>5, lq2 = (k>>3)&3, j = k&7;
    #pragma unroll
    for (int c=0;c<4;++c){
      int n = n0 + tx*4 + c;
      int nt = n>>4, lmn = n&15;
      dst[(((size_t)nt*16 + q)*64 + (lq2*16+lmn))*8 + j] = (f16)acc[a][c];
    }
  }
}

__global__ __launch_bounds__(256) void k_prep_Wx(f16* __restrict__ dst, const float* __restrict__ U, const float* __restrict__ V){
  __shared__ float sU[32][129];
  __shared__ float sV[128][68];
  const int tid = threadIdx.x, n0 = blockIdx.x*64;
  for (int f=tid; f<32*128; f+=256) sU[f>>7][f&127] = U[f];
  for (int f=tid; f<128*64; f+=256) sV[f>>6][f&63] = V[(size_t)(f>>6)*2048 + n0 + (f&63)];
  __syncthreads();
  int nn = tid & 63, kb = (tid>>6)*8;
  int n = n0 + nn;
  float acc[8];
  #pragma unroll
  for (int i=0;i<8;++i) acc[i]=0.f;
  for (int r=0;r<128;++r){
    float v = sV[r][nn];
    #pragma unroll
    for (int i=0;i<8;++i) acc[i] += sU[kb+i][r]*v;
  }
  int nt = n>>4, lmn = n&15;
  #pragma unroll
  for (int i=0;i<8;++i){
    int k = kb+i;
    dst[((size_t)nt*64 + (((k>>3)&3)*16 + lmn))*8 + (k&7)] = (f16)acc[i];
  }
}

__global__ void k_prep_bias(float* dst, const float* a, const float* b){
  int idx = blockIdx.x*256 + threadIdx.x;
  if (idx < 2048) dst[idx] = a[idx] + b[idx];
}

// ---------------- conv block (verified R1-R3) ----------------
__global__ __launch_bounds__(256) void k_conv(
    const float* __restrict__ x0, const f16* __restrict__ zin,
    const float* __restrict__ abp,
    const float* __restrict__ dwk, const float* __restrict__ dwb,
    const float* __restrict__ pwk, const float* __restrict__ pwb,
    f16* __restrict__ zout, float* __restrict__ stats,
    int Lin, int Cin)
{
  const int tid = threadIdx.x;
  const int b = blockIdx.y;
  const int l = blockIdx.x*256 + tid;
  const int Lout = Lin + 2;
  __shared__ float sPw[32*32], sDw[32*7], sDb[32], sPb[32], sAb[64];
  __shared__ float sRed[2][4][32];
  for (int i=tid; i<Cin*32; i+=256) sPw[i] = pwk[i];
  for (int i=tid; i<Cin*7;  i+=256) sDw[i] = dwk[i];
  if (tid < Cin) sDb[tid] = dwb[tid];
  if (tid >= 64 && tid < 96) sPb[tid-64] = pwb[tid-64];
  if (abp != nullptr && tid >= 128 && tid < 192) sAb[tid-128] = abp[tid-128];
  __syncthreads();

  float acc[32];
  #pragma unroll
  for (int o=0;o<32;++o) acc[o] = sPb[o];
  const bool act = (l < Lout);
  if (act){
    for (int c=0;c<Cin;++c){
      float s = sDb[c];
      #pragma unroll
      for (int k=0;k<7;++k){
        int li = l + k - 4;
        float v = 0.f;
        if (li >= 0 && li < Lin){
          if (x0) v = x0[((size_t)b*1024 + li)*16 + c];
          else {
            float z = (float)zin[((size_t)b*32 + c)*LMAX + li];
            v = fmaxf(sAb[c]*z + sAb[32+c], 0.f);
          }
        }
        s += sDw[c*7+k]*v;
      }
      #pragma unroll
      for (int o=0;o<32;++o) acc[o] += sPw[o*Cin + c]*s;
    }
    #pragma unroll
    for (int o=0;o<32;++o) zout[((size_t)b*32 + o)*LMAX + l] = (f16)acc[o];
  }
  const int lane = tid & 63, wv = tid >> 6;
  for (int o=0;o<32;++o){
    float v = act ? acc[o] : 0.f;
    float q = v*v;
    #pragma unroll
    for (int m=1;m<64;m<<=1){ v += __shfl_xor(v,m); q += __shfl_xor(q,m); }
    if (lane == 0){ sRed[0][wv][o] = v; sRed[1][wv][o] = q; }
  }
  __syncthreads();
  if (tid < 32){
    float v = sRed[0][0][tid]+sRed[0][1][tid]+sRed[0][2][tid]+sRed[0][3][tid];
    float q = sRed[1][0][tid]+sRed[1][1][tid]+sRed[1][2][tid]+sRed[1][3][tid];
    atomicAdd(&stats[tid], v);
    atomicAdd(&stats[32+tid], q);
  }
}

__global__ void k_bnfin(const float* __restrict__ stats, const float* __restrict__ g,
                        const float* __restrict__ beta, float* __restrict__ ab, float inv_n)
{
  int o = threadIdx.x;
  if (o < 32){
    float m = stats[o]*inv_n;
    float var = stats[32+o]*inv_n - m*m;
    float a = g[o]*rsqrtf(var + 1e-5f);
    ab[o] = a; ab[32+o] = beta[o] - m*a;
  }
}

// ---------------- y4 precompute ----------------
__global__ __launch_bounds__(256) void k_y4(const f16* __restrict__ z, const float* __restrict__ ab, f16* __restrict__ y){
  __shared__ f16 sT[32][264];
  __shared__ float sA[64];
  const int b = blockIdx.x, t0 = blockIdx.y*256, tid = threadIdx.x;
  if (tid < 64) sA[tid] = ab[tid];
  __syncthreads();
  #pragma unroll
  for (int i=0;i<8;++i){
    int f = tid + 256*i;
    int ch = f >> 6, tq = f & 63;
    int t = t0 + tq*4;
    if (t < 1032){
      u64 v = *(const u64*)(z + ((size_t)(b*32+ch)*1032 + t));
      union { u64 u; f16 h[4]; } cv; cv.u = v;
      float a = sA[ch], bb = sA[32+ch];
      #pragma unroll
      for (int j=0;j<4;++j) cv.h[j] = (f16)fmaxf(a*(float)cv.h[j] + bb, 0.f);
      *(u64*)&sT[ch][tq*4] = cv.u;
    }
  }
  __syncthreads();
  int t = t0 + tid;
  if (t < 1032){
    union { uint4 v; f16 h[8]; } o[4];
    #pragma unroll
    for (int k=0;k<4;++k)
      #pragma unroll
      for (int j=0;j<8;++j) o[k].h[j] = sT[k*8+j][t - t0];
    uint4* dst = (uint4*)(y + ((size_t)b*1032 + t)*32);
    #pragma unroll
    for (int k=0;k<4;++k) dst[k] = o[k].v;
  }
}

// ---------------- persistent 2-layer LSTM: 8 groups x (16 L1 + 16 L2 blocks) ----------------
__global__ __launch_bounds__(256,1) void k_lstm(
  const f16* __restrict__ y4x,
  const f16* __restrict__ Wx1F, const f16* __restrict__ Wh1F,
  const f16* __restrict__ Wi2F, const f16* __restrict__ Wh2F,
  const float* __restrict__ bias1, const float* __restrict__ bias2,
  f16* __restrict__ h1x, f16* __restrict__ h2x,
  uint32_t* __restrict__ flags,
  const float* __restrict__ fcw, const float* __restrict__ fcb,
  float* __restrict__ outp)
{
  const int tid  = threadIdx.x;
  const int lane = tid & 63;
  const int w    = tid >> 6;      // wave = gate index s
  const int lm   = lane & 15;
  const int lq   = lane >> 4;
  const int lq8  = lq*8;
  const int g    = blockIdx.x & 7;              // group (XCD hint)
  const int idx  = blockIdx.x >> 3;             // 0..31
  const int role = idx >> 4;                    // 0 = layer1, 1 = layer2
  const int b    = idx & 15;                    // unit-slice: units b*32..b*32+31

  // 82,432 B static LDS -> exactly 1 block/CU (2x82,432 > 163,840)
  __shared__ __align__(16) uint8_t bufA[32768];
  __shared__ __align__(16) uint8_t bufB[32768];
  __shared__ float sGate[4*32*33];              // padded stride 33

  uint32_t* fl = flags + (size_t)g*32;          // [0..15]=FH1(producers), [16..31]=FHC(consumers)

  const float* biasL = role ? bias2 : bias1;
  float bs[2];
  #pragma unroll
  for (int ct=0; ct<2; ++ct) bs[ct] = biasL[w*512 + b*32 + ct*16 + lm];

  const int nt0 = w*32 + b*2;
  f16* hdst_base = role ? h2x + (size_t)g*4*32*512 : h1x + (size_t)g*8*32*512;

  float creg[4] = {0.f,0.f,0.f,0.f};
  const int cr_row = tid >> 3, cr_u0 = (tid & 7)*4;

  if (role == 0){
    // ---------------- layer-1 producer (verified, unchanged) ----------------
    half8 wx[2];
    half8 wB[2][16];
    #pragma unroll
    for (int ct=0; ct<2; ++ct){
      wx[ct] = *(const half8*)&Wx1F[((size_t)(nt0+ct)*64 + lane)*8];
      #pragma unroll
      for (int q=0;q<16;++q)
        wB[ct][q] = *(const half8*)&Wh1F[(((size_t)(nt0+ct)*16 + q)*64 + lane)*8];
    }
    #pragma unroll 1
    for (int t=0; t<TSTEPS; ++t){
      // y4 prefetch (independent of flags)
      half8 ya0 = *(const half8*)(y4x + ((size_t)(g*32 + lm)*1032 + t)*32 + lq8);
      half8 ya1 = *(const half8*)(y4x + ((size_t)(g*32 + 16 + lm)*1032 + t)*32 + lq8);
      if (w == 0) pollWave(fl, t, t-7);   // peers' h1(t-1); consumers done t-8
      __syncthreads();
      float4 st[8];
      if (t >= 1) stageIssue(st, h1x + ((size_t)(g*8 + ((t-1)&7))*32*512), tid);
      floatx4 acc[2][2];
      #pragma unroll
      for (int ct=0; ct<2; ++ct){
        acc[ct][0] = (floatx4){bs[ct],bs[ct],bs[ct],bs[ct]};
        acc[ct][1] = acc[ct][0];
      }
      acc[0][0] = MFMA(ya0, wx[0], acc[0][0]);
      acc[0][1] = MFMA(ya1, wx[0], acc[0][1]);
      acc[1][0] = MFMA(ya0, wx[1], acc[1][0]);
      acc[1][1] = MFMA(ya1, wx[1], acc[1][1]);
      if (t >= 1){
        vmcnt0();
        stageWrite(bufA, st, tid);
      }
      __syncthreads();
      if (t >= 1){
        #pragma unroll
        for (int q=0;q<16;++q){
          half8 a0 = fragLDS(bufA, lm,    q, lq);
          half8 a1 = fragLDS(bufA, 16+lm, q, lq);
          acc[0][0] = MFMA(a0, wB[0][q], acc[0][0]);
          acc[0][1] = MFMA(a1, wB[0][q], acc[0][1]);
          acc[1][0] = MFMA(a0, wB[1][q], acc[1][0]);
          acc[1][1] = MFMA(a1, wB[1][q], acc[1][1]);
        }
      }
      __syncthreads();
      #pragma unroll
      for (int ct=0; ct<2; ++ct)
        #pragma unroll
        for (int rt=0; rt<2; ++rt)
          #pragma unroll
          for (int r=0;r<4;++r)
            sGate[w*1056 + (rt*16 + lq*4 + r)*33 + ct*16 + lm] = acc[ct][rt][r];
      __syncthreads();
      {
        union { u64 uu; f16 h[4]; } hv;
        #pragma unroll
        for (int j=0;j<4;++j){
          int u = cr_u0 + j;
          float iv = sGate[0*1056 + cr_row*33 + u];
          float fv = sGate[1*1056 + cr_row*33 + u];
          float gv = sGate[2*1056 + cr_row*33 + u];
          float ov = sGate[3*1056 + cr_row*33 + u];
          float c = sigm(fv)*creg[j] + sigm(iv)*tanh_f(gv);
          creg[j] = c;
          hv.h[j] = (f16)(sigm(ov)*tanh_f(c));
        }
        f16* dst = hdst_base + (size_t)(t&7)*32*512 + cr_row*512 + b*32 + cr_u0;
        sta64(dst, hv.uu);
      }
      vmcnt0();
      __syncthreads();
      if (tid == 0) stf(&fl[b], (uint32_t)(t+1));
    }
  } else {
    // ---------------- layer-2 consumer: counted-vmcnt overlap ----------------
    // Issue h2 loads then h1 loads; vmcnt(8) waits only h2 -> B-part MFMAs run
    // while the h1 leg completes underneath; raw s_barrier keeps loads in flight.
    half8 wA[2][16];
    half8 wB[2][16];
    #pragma unroll
    for (int ct=0; ct<2; ++ct)
      #pragma unroll
      for (int q=0;q<16;++q){
        wA[ct][q] = *(const half8*)&Wi2F[(((size_t)(nt0+ct)*16 + q)*64 + lane)*8];
        wB[ct][q] = *(const half8*)&Wh2F[(((size_t)(nt0+ct)*16 + q)*64 + lane)*8];
      }
    #pragma unroll 1
    for (int t=0; t<TSTEPS; ++t){
      if (w == 0) pollWave(fl, t+1, t);   // producers done t; consumer peers done t-1
      __syncthreads();
      float4 s0[8], s1[8];
      floatx4 acc[2][2];
      #pragma unroll
      for (int ct=0; ct<2; ++ct){
        acc[ct][0] = (floatx4){bs[ct],bs[ct],bs[ct],bs[ct]};
        acc[ct][1] = acc[ct][0];
      }
      if (t >= 1){
        stageIssue(s1, h2x + ((size_t)(g*4 + ((t-1)&3))*32*512), tid);  // oldest 8: h2
        stageIssue(s0, h1x + ((size_t)(g*8 + (t&7))*32*512), tid);      // next 8: h1
        vmcnt8();            // wait h2 only; h1 stays in flight
        schedbar();
        stageWrite(bufB, s1, tid);
        lgkm0();
        __builtin_amdgcn_s_barrier();
        schedbar();
        #pragma unroll
        for (int q=0;q<16;++q){
          half8 a0 = fragLDS(bufB, lm,    q, lq);
          half8 a1 = fragLDS(bufB, 16+lm, q, lq);
          acc[0][0] = MFMA(a0, wB[0][q], acc[0][0]);
          acc[0][1] = MFMA(a1, wB[0][q], acc[0][1]);
          acc[1][0] = MFMA(a0, wB[1][q], acc[1][0]);
          acc[1][1] = MFMA(a1, wB[1][q], acc[1][1]);
        }
        vmcnt0();            // h1 leg: hidden under the 64 B-part MFMAs
        schedbar();
        stageWrite(bufA, s0, tid);
        lgkm0();
        __builtin_amdgcn_s_barrier();
        schedbar();
      } else {
        stageIssue(s0, h1x + ((size_t)(g*8 + (t&7))*32*512), tid);
        vmcnt0();
        schedbar();
        stageWrite(bufA, s0, tid);
        lgkm0();
        __builtin_amdgcn_s_barrier();
        schedbar();
      }
      #pragma unroll
      for (int q=0;q<16;++q){
        half8 a0 = fragLDS(bufA, lm,    q, lq);
        half8 a1 = fragLDS(bufA, 16+lm, q, lq);
        acc[0][0] = MFMA(a0, wA[0][q], acc[0][0]);
        acc[0][1] = MFMA(a1, wA[0][q], acc[0][1]);
        acc[1][0] = MFMA(a0, wA[1][q], acc[1][0]);
        acc[1][1] = MFMA(a1, wA[1][q], acc[1][1]);
      }
      __syncthreads();
      #pragma unroll
      for (int ct=0; ct<2; ++ct)
        #pragma unroll
        for (int rt=0; rt<2; ++rt)
          #pragma unroll
          for (int r=0;r<4;++r)
            sGate[w*1056 + (rt*16 + lq*4 + r)*33 + ct*16 + lm] = acc[ct][rt][r];
      __syncthreads();
      {
        union { u64 uu; f16 h[4]; } hv;
        #pragma unroll
        for (int j=0;j<4;++j){
          int u = cr_u0 + j;
          float iv = sGate[0*1056 + cr_row*33 + u];
          float fv = sGate[1*1056 + cr_row*33 + u];
          float gv = sGate[2*1056 + cr_row*33 + u];
          float ov = sGate[3*1056 + cr_row*33 + u];
          float c = sigm(fv)*creg[j] + sigm(iv)*tanh_f(gv);
          creg[j] = c;
          hv.h[j] = (f16)(sigm(ov)*tanh_f(c));
        }
        f16* dst = hdst_base + (size_t)(t&3)*32*512 + cr_row*512 + b*32 + cr_u0;
        sta64(dst, hv.uu);
      }
      vmcnt0();
      __syncthreads();
      if (tid == 0) stf(&fl[16 + b], (uint32_t)(t+1));
    }
    // ---------- epilogue: out = h2(T-1) @ fc_w^T + fc_b ----------
    if (b == 0){
      if (w == 0) pollWave(fl, 0, TSTEPS);
      __syncthreads();
      const f16* hbase = h2x + ((size_t)(g*4 + ((TSTEPS-1)&3))*32*512);
      for (int e = tid; e < 320; e += 256){
        int row = e/10, nc = e%10;
        float s = fcb[nc];
        const float* wv = fcw + (size_t)nc*512;
        const u64* hp = (const u64*)(hbase + row*512);
        for (int k4=0;k4<128;++k4){
          union { u64 uu; f16 h[4]; } cv; cv.uu = lda64(hp + k4);
          #pragma unroll
          for (int i2=0;i2<4;++i2) s += (float)cv.h[i2]*wv[k4*4+i2];
        }
        outp[(size_t)(g*32+row)*10 + nc] = s;
      }
    }
  }
}

// ---------------- host ----------------
extern "C" void kernel_launch(void* const* d_in, const int* in_sizes, int n_in,
                              void* d_out, int out_size, void* d_ws, size_t ws_size,
                              hipStream_t stream)
{
  (void)in_sizes; (void)n_in; (void)out_size; (void)ws_size;
  const float* x = (const float*)d_in[0];
  auto F = [&](int i){ return (const float*)d_in[i]; };
  const float *Ui1=F(25), *Vi1=F(26), *Uh1=F(27), *Vh1=F(28), *bi1=F(29), *bh1=F(30);
  const float *Ui2=F(31), *Vi2=F(32), *Uh2=F(33), *Vh2=F(34), *bi2=F(35), *bh2=F(36);
  const float *fcw=F(37), *fcb=F(38);

  uint8_t* ws = (uint8_t*)d_ws;
  f16* zA   = (f16*)(ws + OFF_ZA);
  f16* zB   = (f16*)(ws + OFF_ZB);
  f16* y4x  = (f16*)(ws + OFF_Y4);
  f16* Wh1F = (f16*)(ws + OFF_WH1F);
  f16* Wi2F = (f16*)(ws + OFF_WI2F);
  f16* Wh2F = (f16*)(ws + OFF_WH2F);
  f16* Wx1F = (f16*)(ws + OFF_WX1F);
  float* bias1 = (float*)(ws + OFF_B1);
  float* bias2 = (float*)(ws + OFF_B2);
  float* stats = (float*)(ws + OFF_STATS);
  float* ab    = (float*)(ws + OFF_AB);
  f16* h1x  = (f16*)(ws + OFF_H1X);
  f16* h2x  = (f16*)(ws + OFF_H2X);
  uint32_t* flags = (uint32_t*)(ws + OFF_FLAGS);
  float* outp = (float*)d_out;

  k_zero<<<5, 256, 0, stream>>>(stats, flags);

  k_prep_W<<<dim3(32,8), 256, 0, stream>>>(Wh1F, Uh1, Vh1);
  k_prep_W<<<dim3(32,8), 256, 0, stream>>>(Wi2F, Ui2, Vi2);
  k_prep_W<<<dim3(32,8), 256, 0, stream>>>(Wh2F, Uh2, Vh2);
  k_prep_Wx<<<32, 256, 0, stream>>>(Wx1F, Ui1, Vi1);
  k_prep_bias<<<8, 256, 0, stream>>>(bias1, bi1, bh1);
  k_prep_bias<<<8, 256, 0, stream>>>(bias2, bi2, bh2);

  dim3 cgrid(5, 256);
  k_conv<<<cgrid, 256, 0, stream>>>(x, nullptr, nullptr, F(1), F(2), F(3), F(4),
                                    zA, stats + 0*64, 1024, 16);
  k_bnfin<<<1, 64, 0, stream>>>(stats + 0*64, F(5), F(6), ab + 0*64, 1.f/(256.f*1026.f));
  k_conv<<<cgrid, 256, 0, stream>>>(nullptr, zA, ab + 0*64, F(7), F(8), F(9), F(10),
                                    zB, stats + 1*64, 1026, 32);
  k_bnfin<<<1, 64, 0, stream>>>(stats + 1*64, F(11), F(12), ab + 1*64, 1.f/(256.f*1028.f));
  k_conv<<<cgrid, 256, 0, stream>>>(nullptr, zB, ab + 1*64, F(13), F(14), F(15), F(16),
                                    zA, stats + 2*64, 1028, 32);
  k_bnfin<<<1, 64, 0, stream>>>(stats + 2*64, F(17), F(18), ab + 2*64, 1.f/(256.f*1030.f));
  k_conv<<<cgrid, 256, 0, stream>>>(nullptr, zA, ab + 2*64, F(19), F(20), F(21), F(22),
                                    zB, stats + 3*64, 1030, 32);
  k_bnfin<<<1, 64, 0, stream>>>(stats + 3*64, F(23), F(24), ab + 3*64, 1.f/(256.f*1032.f));

  k_y4<<<dim3(256,5), 256, 0, stream>>>(zB, ab + 3*64, y4x);

  k_lstm<<<256, 256, 0, stream>>>(y4x,
                                  Wx1F, Wh1F, Wi2F, Wh2F,
                                  bias1, bias2,
                                  h1x, h2x, flags,
                                  fcw, fcb, outp);
}